// Round 1
// 1405.035 us; speedup vs baseline: 1.0913x; 1.0913x over previous
//
#include <hip/hip_runtime.h>
#include <hip/hip_bf16.h>
#include <math.h>

typedef __hip_bfloat16 bf16;
typedef __bf16 bf16x8 __attribute__((ext_vector_type(8)));
typedef float f32x4 __attribute__((ext_vector_type(4)));
typedef unsigned short ushort_t;

// Problem constants: B=4, S=2048, H=1024, K=64, NH=16, d=64, L=2, FF=2730 (pad 2816), EPS=1e-6
// Inputs fp32, output fp32. Decoder big GEMMs: bf16 MFMA (m97 structure).
// Small-M (M=256) GEMMs: fp32 split-K (Kc=128) + reduce.
// Round 5: mfma_gated_k was occupancy-starved (128 acc regs + 136 VGPR -> 1 wave/SIMD,
// MfmaUtil 15%, 250us). Restructured to 8 waves x (64x32 per-wave tile): 64 acc regs,
// __launch_bounds__(512,4) caps at 128 regs -> 2 blocks/CU, cross-block drain overlap.

__device__ __forceinline__ float ldf(const float* p, long i){ return p[i]; }
__device__ __forceinline__ void  stf(float* p, long i, float v){ p[i] = v; }
__device__ __forceinline__ void  stf(bf16*  p, long i, float v){ p[i] = __float2bfloat16(v); }

#define AS1 __attribute__((address_space(1)))
#define AS3 __attribute__((address_space(3)))

__device__ __forceinline__ void gl2lds16(const void* g, void* l){
    __builtin_amdgcn_global_load_lds((const AS1 void*)g, (AS3 void*)l, 16, 0, 0);
}

// ---------------- fp32 -> bf16 conversion with optional zero-padding -------------
__global__ __launch_bounds__(256) void cvt_pad_k(const float* __restrict__ src,
                                                 bf16* __restrict__ dst,
                                                 int rows_in, int cols_in, int cols_out){
    int r = blockIdx.x;
    const float* s = src + (long)r*cols_in;
    bf16* d = dst + (long)r*cols_out;
    bool rowok = r < rows_in;
    for (int c = threadIdx.x; c < cols_out; c += 256){
        float v = (rowok && c < cols_in) ? s[c] : 0.f;
        d[c] = __float2bfloat16(v);
    }
}

// ---------------- MFMA GEMM: C(fp32) = A(bf16,MxKd) @ W(bf16,NxKd)^T (+bias)(+Res)
__global__ __launch_bounds__(256) void mfma_gemm_k(
    const bf16* __restrict__ A, const bf16* __restrict__ W,
    const float* __restrict__ bias, const float* __restrict__ Res,
    float* __restrict__ C, int N, int Kd)
{
    __shared__ __align__(16) ushort_t As[128*32];
    __shared__ __align__(16) ushort_t Bs[128*32];
    const int tid = threadIdx.x;
    const int lane = tid & 63, wave = tid >> 6;
    const int wm = wave >> 1, wn = wave & 1;
    const int kg = lane >> 4, ln = lane & 15;
    const long bm = (long)blockIdx.y * 128, bn = (long)blockIdx.x * 128;

    const int srow = tid >> 2;
    const int scol = (tid & 3) * 8;
    const ushort_t* Ag = (const ushort_t*)A + (bm + srow)*(long)Kd + scol;
    const ushort_t* Wg = (const ushort_t*)W + (bn + srow)*(long)Kd + scol;
    ushort_t* Asd = &As[tid*8];
    ushort_t* Bsd = &Bs[tid*8];

    f32x4 acc[4][4] = {};
    for (int k0 = 0; k0 < Kd; k0 += 32){
        gl2lds16(Ag,               Asd);
        gl2lds16(Ag + (long)64*Kd, Asd + 2048);
        gl2lds16(Wg,               Bsd);
        gl2lds16(Wg + (long)64*Kd, Bsd + 2048);
        Ag += 32; Wg += 32;
        __syncthreads();
        bf16x8 af[4], bfr[4];
        #pragma unroll
        for (int t = 0; t < 4; t++){
            af[t]  = *(const bf16x8*)&As[(wm*64 + t*16 + ln)*32 + kg*8];
            bfr[t] = *(const bf16x8*)&Bs[(wn*64 + t*16 + ln)*32 + kg*8];
        }
        #pragma unroll
        for (int i = 0; i < 4; i++)
            #pragma unroll
            for (int j = 0; j < 4; j++)
                acc[i][j] = __builtin_amdgcn_mfma_f32_16x16x32_bf16(af[i], bfr[j], acc[i][j], 0, 0, 0);
        __syncthreads();
    }
    #pragma unroll
    for (int i = 0; i < 4; i++){
        long gm0 = bm + wm*64 + i*16 + kg*4;
        #pragma unroll
        for (int j = 0; j < 4; j++){
            long gn = bn + wn*64 + j*16 + ln;
            float bv = bias ? bias[gn] : 0.f;
            #pragma unroll
            for (int r = 0; r < 4; r++){
                long gm = gm0 + r;
                float v = acc[i][j][r] + bv;
                if (Res) v += Res[gm*N + gn];
                C[gm*N + gn] = v;
            }
        }
    }
}

// ---------------- MFMA gated GEMM: C(bf16) = silu(A@W1^T) * (A@W3^T) -------------
// 8 waves (512 thr), 128x128 block tile, per-wave 64x32 output => 64 acc regs/wave.
// launch_bounds(512,4): cap 128 regs -> 2 blocks/CU for cross-block drain overlap.
__global__ __launch_bounds__(512, 4) void mfma_gated_k(
    const bf16* __restrict__ A, const bf16* __restrict__ W1,
    const bf16* __restrict__ W3, bf16* __restrict__ C, int Kd, int Nstride)
{
    __shared__ __align__(16) ushort_t As[128*32];
    __shared__ __align__(16) ushort_t B1s[128*32];
    __shared__ __align__(16) ushort_t B3s[128*32];
    const int tid = threadIdx.x;
    const int lane = tid & 63, wave = tid >> 6;   // 8 waves
    const int wm = wave >> 2, wn = wave & 3;      // 2 (row-halves) x 4 (col-quarters)
    const int kg = lane >> 4, ln = lane & 15;
    const long bm = (long)blockIdx.y * 128, bn = (long)blockIdx.x * 128;

    const int srow = tid >> 2;                    // 512 thr cover 128 rows x 32 cols
    const int scol = (tid & 3) * 8;
    const ushort_t* Ag  = (const ushort_t*)A  + (bm + srow)*(long)Kd + scol;
    const ushort_t* W1g = (const ushort_t*)W1 + (bn + srow)*(long)Kd + scol;
    const ushort_t* W3g = (const ushort_t*)W3 + (bn + srow)*(long)Kd + scol;
    ushort_t* Asd  = &As[tid*8];
    ushort_t* B1sd = &B1s[tid*8];
    ushort_t* B3sd = &B3s[tid*8];

    f32x4 acc1[4][2] = {};
    f32x4 acc3[4][2] = {};
    for (int k0 = 0; k0 < Kd; k0 += 32){
        gl2lds16(Ag,  Asd);
        gl2lds16(W1g, B1sd);
        gl2lds16(W3g, B3sd);
        Ag += 32; W1g += 32; W3g += 32;
        __syncthreads();
        bf16x8 af[4], b1[2], b3[2];
        #pragma unroll
        for (int t = 0; t < 4; t++)
            af[t] = *(const bf16x8*)&As[(wm*64 + t*16 + ln)*32 + kg*8];
        #pragma unroll
        for (int j = 0; j < 2; j++){
            b1[j] = *(const bf16x8*)&B1s[(wn*32 + j*16 + ln)*32 + kg*8];
            b3[j] = *(const bf16x8*)&B3s[(wn*32 + j*16 + ln)*32 + kg*8];
        }
        #pragma unroll
        for (int i = 0; i < 4; i++)
            #pragma unroll
            for (int j = 0; j < 2; j++){
                acc1[i][j] = __builtin_amdgcn_mfma_f32_16x16x32_bf16(af[i], b1[j], acc1[i][j], 0, 0, 0);
                acc3[i][j] = __builtin_amdgcn_mfma_f32_16x16x32_bf16(af[i], b3[j], acc3[i][j], 0, 0, 0);
            }
        __syncthreads();
    }
    #pragma unroll
    for (int i = 0; i < 4; i++){
        long gm0 = bm + wm*64 + i*16 + kg*4;
        #pragma unroll
        for (int j = 0; j < 2; j++){
            long gn = bn + wn*32 + j*16 + ln;
            #pragma unroll
            for (int r = 0; r < 4; r++){
                float x1 = acc1[i][j][r];
                float g  = x1 / (1.0f + expf(-x1));
                C[(gm0 + r)*Nstride + gn] = __float2bfloat16(g * acc3[i][j][r]);
            }
        }
    }
}

// ---------------- fp32 split-K GEMM: P[kz] = A(MxKd) @ W(NxKd)^T chunk -----------
// grid (N/64, M/64, KS), Kc per z-chunk. Partials, no bias/res.
__global__ __launch_bounds__(256) void gemm_sk_k(
    const float* __restrict__ A, const float* __restrict__ W,
    float* __restrict__ P, int M, int N, int Kd, int Kc)
{
    __shared__ float As[16][65];
    __shared__ float Ws[16][65];
    const int bm = blockIdx.y*64, bn = blockIdx.x*64;
    const int kz = blockIdx.z;
    const int kbeg = kz*Kc, kend = min(kbeg + Kc, Kd);
    const int tid = threadIdx.x;
    const int tx = tid & 15, ty = tid >> 4;
    float acc[4][4] = {};
    for (int k0 = kbeg; k0 < kend; k0 += 16){
        for (int e = tid; e < 1024; e += 256){
            int m = e >> 4, kk = e & 15;
            int gk = k0 + kk;
            int gm = bm + m;
            int gn = bn + m;
            As[kk][m] = (gm < M && gk < kend) ? A[(long)gm*Kd + gk] : 0.f;
            Ws[kk][m] = (gn < N && gk < kend) ? W[(long)gn*Kd + gk] : 0.f;
        }
        __syncthreads();
        #pragma unroll
        for (int kk = 0; kk < 16; kk++){
            float a[4], b[4];
            #pragma unroll
            for (int i = 0; i < 4; i++) a[i] = As[kk][ty*4+i];
            #pragma unroll
            for (int j = 0; j < 4; j++) b[j] = Ws[kk][tx*4+j];
            #pragma unroll
            for (int i = 0; i < 4; i++)
                #pragma unroll
                for (int j = 0; j < 4; j++)
                    acc[i][j] = fmaf(a[i], b[j], acc[i][j]);
        }
        __syncthreads();
    }
    float* Pz = P + (long)kz*M*N;
    #pragma unroll
    for (int i = 0; i < 4; i++){
        int m = bm + ty*4 + i;
        if (m >= M) continue;
        #pragma unroll
        for (int j = 0; j < 4; j++){
            int n = bn + tx*4 + j;
            if (n >= N) continue;
            Pz[(long)m*N + n] = acc[i][j];
        }
    }
}

// ---------------- reduce: C = sum_ks P (+bias)(+Res) ------------------------------
__global__ __launch_bounds__(256) void reduce_plain_k(
    const float* __restrict__ P, int KS, const float* __restrict__ bias,
    const float* __restrict__ Res, float* __restrict__ C, long MN, int N)
{
    long i = (long)blockIdx.x*256 + threadIdx.x;
    if (i >= MN) return;
    float s = 0.f;
    for (int k = 0; k < KS; k++) s += P[(long)k*MN + i];
    if (bias) s += bias[i % N];
    if (Res)  s += Res[i];
    C[i] = s;
}

// ---------------- reduce gated: C = silu(sum P1) * (sum P3) -----------------------
__global__ __launch_bounds__(256) void reduce_gated_k(
    const float* __restrict__ P1, const float* __restrict__ P3, int KS,
    float* __restrict__ C, long MN)
{
    long i = (long)blockIdx.x*256 + threadIdx.x;
    if (i >= MN) return;
    float s1 = 0.f, s3 = 0.f;
    for (int k = 0; k < KS; k++){ s1 += P1[(long)k*MN + i]; s3 += P3[(long)k*MN + i]; }
    float g = s1 / (1.0f + expf(-s1));
    C[i] = g * s3;
}

// ---------------- stable descending argsort of chunk_weights (K=64) -------------
__global__ void sort_chunks_k(const float* __restrict__ w, int* __restrict__ sidx){
    int b = blockIdx.x, t = threadIdx.x;
    __shared__ float ws_[64];
    ws_[t] = w[b*64 + t];
    __syncthreads();
    float mine = ws_[t];
    int rank = 0;
    for (int j = 0; j < 64; j++){
        float wj = ws_[j];
        rank += (wj > mine) || (wj == mine && j < t);
    }
    sidx[b*64 + rank] = t;
}

__global__ void gather_k(const float* __restrict__ src, const int* __restrict__ sidx,
                         float* __restrict__ dst){
    int row = blockIdx.x; int b = row >> 6, r = row & 63;
    int sr = sidx[b*64 + r];
    const float* s = src + ((long)(b*64 + sr))*1024;
    float* d = dst + (long)row*1024;
    for (int i = threadIdx.x; i < 1024; i += 256) d[i] = s[i];
}

__global__ void scatter_k(const float* __restrict__ x, const int* __restrict__ sidx,
                          float* __restrict__ proc){
    int row = blockIdx.x; int b = row >> 6, r = row & 63;
    int dr = sidx[b*64 + r];
    const float* s = x + (long)row*1024;
    float* d = proc + ((long)(b*64 + dr))*1024;
    for (int i = threadIdx.x; i < 1024; i += 256) d[i] = s[i];
}

// ---------------- RMSNorm (row length fixed 1024) --------------------------------
template<typename TO>
__global__ __launch_bounds__(256) void rms_k(const float* __restrict__ x,
                                             const float* __restrict__ w,
                                             TO* __restrict__ o){
    long row = blockIdx.x;
    const float* xr = x + row*1024;
    float v[4]; float ss = 0.f;
    #pragma unroll
    for (int j = 0; j < 4; j++){ v[j] = xr[threadIdx.x + j*256]; ss += v[j]*v[j]; }
    #pragma unroll
    for (int off = 32; off; off >>= 1) ss += __shfl_down(ss, off, 64);
    __shared__ float red[4];
    __shared__ float scale_s;
    int wave = threadIdx.x >> 6, lane = threadIdx.x & 63;
    if (lane == 0) red[wave] = ss;
    __syncthreads();
    if (threadIdx.x == 0){
        float t = red[0] + red[1] + red[2] + red[3];
        scale_s = rsqrtf(t * (1.0f/1024.f) + 1e-6f);
    }
    __syncthreads();
    float sc = scale_s;
    #pragma unroll
    for (int j = 0; j < 4; j++){
        int i = threadIdx.x + j*256;
        stf(o, row*1024 + i, v[j] * sc * w[i]);
    }
}

// ---------------- Cascade causal self-attention (K=64, d=64, per (b,h)) ----------
__global__ __launch_bounds__(64) void casc_attn_k(const float* __restrict__ qkv,
                                                  float* __restrict__ o){
    int b = blockIdx.x >> 4, h = blockIdx.x & 15;
    __shared__ float Ks[64][64], Vs[64][64], Sc[64][64];
    int t = threadIdx.x;
    const float* base = qkv + ((long)(b*64 + t))*3072 + h*64;
    float qr[64];
    #pragma unroll
    for (int i = 0; i < 64; i++){
        qr[i]    = base[i];
        Ks[t][i] = base[1024 + i];
        Vs[t][i] = base[2048 + i];
    }
    __syncthreads();
    float m = -1e30f;
    for (int j = 0; j <= t; j++){
        float dot = 0.f;
        #pragma unroll
        for (int i = 0; i < 64; i++) dot = fmaf(qr[i], Ks[j][i], dot);
        dot *= 0.125f;
        Sc[t][j] = dot;
        m = fmaxf(m, dot);
    }
    float l = 0.f;
    for (int j = 0; j <= t; j++){ float e = expf(Sc[t][j] - m); Sc[t][j] = e; l += e; }
    float inv = 1.f / l;
    float* op = o + ((long)(b*64 + t))*1024 + h*64;
    for (int i = 0; i < 64; i++){
        float acc = 0.f;
        for (int j = 0; j <= t; j++) acc = fmaf(Sc[t][j], Vs[j][i], acc);
        op[i] = acc * inv;
    }
}

// ---------------- Decoder cross-attention -> bf16 output -------------------------
__global__ __launch_bounds__(256) void dec_attn_k(const float* __restrict__ q,
    const float* __restrict__ kk, const float* __restrict__ vv, bf16* __restrict__ o){
    int s0 = blockIdx.x*64, h = blockIdx.y, b = blockIdx.z;
    __shared__ float Ks[64][64], Vs[64][64], Sc[64][65];
    int tid = threadIdx.x;
    for (int e = tid; e < 4096; e += 256){
        int c = e >> 6, i = e & 63;
        Ks[c][i] = kk[((long)(b*64 + c))*1024 + h*64 + i];
        Vs[c][i] = vv[((long)(b*64 + c))*1024 + h*64 + i];
    }
    __syncthreads();
    int r = tid >> 2, seg = tid & 3;
    int s = s0 + r;
    float qr[64];
    const float* qp = q + ((long)(b*2048 + s))*1024 + h*64;
    #pragma unroll
    for (int i = 0; i < 64; i++) qr[i] = qp[i];
    int cmax = s/32 + 1;
    for (int c = seg*16; c < seg*16 + 16; c++){
        float dot = 0.f;
        #pragma unroll
        for (int i = 0; i < 64; i++) dot = fmaf(qr[i], Ks[c][i], dot);
        Sc[r][c] = (c <= cmax) ? dot*0.125f : -1e30f;
    }
    __syncthreads();
    if (tid < 64){
        float m = -1e30f;
        for (int c = 0; c < 64; c++) m = fmaxf(m, Sc[tid][c]);
        float l = 0.f;
        for (int c = 0; c < 64; c++){ float e = expf(Sc[tid][c] - m); Sc[tid][c] = e; l += e; }
        float inv = 1.f / l;
        for (int c = 0; c < 64; c++) Sc[tid][c] *= inv;
    }
    __syncthreads();
    float accv[16] = {};
    for (int c = 0; c < 64; c++){
        float p = Sc[r][c];
        #pragma unroll
        for (int i = 0; i < 16; i++) accv[i] = fmaf(p, Vs[c][seg*16 + i], accv[i]);
    }
    bf16* op = o + ((long)(b*2048 + s))*1024 + h*64 + seg*16;
    #pragma unroll
    for (int i = 0; i < 16; i++) op[i] = __float2bfloat16(accv[i]);
}

// ---------------------------------------------------------------------------------
extern "C" void kernel_launch(void* const* d_in, const int* in_sizes, int n_in,
                              void* d_out, int out_size, void* d_ws, size_t ws_size,
                              hipStream_t stream)
{
    const float* tok   = (const float*)d_in[0];
    const float* crepr = (const float*)d_in[1];
    const float* cw    = (const float*)d_in[2];
    const float* n1    = (const float*)d_in[3];
    const float* cqkv  = (const float*)d_in[4];
    const float* co    = (const float*)d_in[5];
    const float* n2    = (const float*)d_in[6];
    const float* cw1   = (const float*)d_in[7];
    const float* cw2   = (const float*)d_in[8];
    const float* cw3   = (const float*)d_in[9];
    const float* dinw  = (const float*)d_in[10];
    const float* dinb  = (const float*)d_in[11];
    const float* doutw = (const float*)d_in[12];
    const float* doutb = (const float*)d_in[13];
    const float* dnw   = (const float*)d_in[14];
    const float* dfnw  = (const float*)d_in[15];
    const float* dw1   = (const float*)d_in[16];
    const float* dw2   = (const float*)d_in[17];
    const float* dw3   = (const float*)d_in[18];
    float* out = (float*)d_out;

    // Workspace layout (float units). Same total as round 4 (~180 MB).
    float* F = (float*)d_ws;
    long off = 0;
    int*   sidx  = (int*)d_ws;        off += 1024;
    float* x_c   = F + off;           off += 262144;    // 256x1024
    float* h_c   = F + off;           off += 262144;
    float* qkv_c = F + off;           off += 786432;    // 256x3072
    float* o_c   = F + off;           off += 262144;
    float* g_c   = F + off;           off += 698880;    // 256x2730
    float* proc  = F + off;           off += 262144;
    float* kkb   = F + off;           off += 262144;
    float* vvb   = F + off;           off += 262144;
    float* q_d   = F + off;           off += 8388608;   // 8192x1024 fp32
    float* y1    = F + off;           off += 8388608;   // 8192x1024 fp32
    bf16*  tok_bf= (bf16*)(F + off);  off += 4194304;   // 8192x1024 bf16
    bf16*  att_bf= (bf16*)(F + off);  off += 4194304;   // 8192x1024 bf16
    bf16*  wq_bf = (bf16*)(F + off);  off += 524288;    // 1024x1024 bf16
    bf16*  wo_bf = (bf16*)(F + off);  off += 524288;
    bf16*  w1_bf = (bf16*)(F + off);  off += 1441792;   // 2816x1024 bf16
    bf16*  w3_bf = (bf16*)(F + off);  off += 1441792;
    bf16*  w2_bf = (bf16*)(F + off);  off += 1441792;   // 1024x2816 bf16
    float* t1    = F + off;
    bf16*  g_d   = (bf16*)(F + off);  off += 11534336;  // 8192x2816 bf16 (t1 overlays)
    bf16*  x2_bf = tok_bf;                              // reuse after q-proj

    // Split-K partial pool: aliases q_d..y1 (16.78M floats, dead during cascade +
    // k/v projections, which all complete before q-proj writes q_d).
    float* P  = q_d;                  // up to ~11.2M floats used
    float* P3 = q_d + 5591040;        // second gated partial (8*256*2730)

    // ---- bf16 conversions (decoder weights/activations) ----
    cvt_pad_k<<<8192, 256, 0, stream>>>(tok,   tok_bf, 8192, 1024, 1024);
    cvt_pad_k<<<1024, 256, 0, stream>>>(dinw,  wq_bf,  1024, 1024, 1024);
    cvt_pad_k<<<1024, 256, 0, stream>>>(doutw, wo_bf,  1024, 1024, 1024);
    cvt_pad_k<<<2816, 256, 0, stream>>>(dw1,   w1_bf,  2730, 1024, 1024);
    cvt_pad_k<<<2816, 256, 0, stream>>>(dw3,   w3_bf,  2730, 1024, 1024);
    cvt_pad_k<<<1024, 256, 0, stream>>>(dw2,   w2_bf,  1024, 2730, 2816);

    // ---- Cascade processor (fp32 split-K) ----
    sort_chunks_k<<<4, 64, 0, stream>>>(cw, sidx);
    gather_k<<<256, 256, 0, stream>>>(crepr, sidx, x_c);
    for (int l = 0; l < 2; l++){
        rms_k<float><<<256, 256, 0, stream>>>(x_c, n1 + l*1024, h_c);
        // qkv: 256x3072 = h @ cqkv^T, K=1024, KS=8
        gemm_sk_k<<<dim3(48,4,8), 256, 0, stream>>>(
            h_c, cqkv + (long)l*3145728, P, 256, 3072, 1024, 128);
        reduce_plain_k<<<3072, 256, 0, stream>>>(P, 8, nullptr, nullptr, qkv_c, 786432, 3072);
        casc_attn_k<<<64, 64, 0, stream>>>(qkv_c, o_c);
        // o-proj: x += o @ co^T, K=1024, KS=8
        gemm_sk_k<<<dim3(16,4,8), 256, 0, stream>>>(
            o_c, co + (long)l*1048576, P, 256, 1024, 1024, 128);
        reduce_plain_k<<<1024, 256, 0, stream>>>(P, 8, nullptr, x_c, x_c, 262144, 1024);
        rms_k<float><<<256, 256, 0, stream>>>(x_c, n2 + l*1024, h_c);
        // gated FFN: P1 = h@w1^T, P3 = h@w3^T (N=2730, 43 n-tiles), KS=8
        gemm_sk_k<<<dim3(43,4,8), 256, 0, stream>>>(
            h_c, cw1 + (long)l*2795520, P,  256, 2730, 1024, 128);
        gemm_sk_k<<<dim3(43,4,8), 256, 0, stream>>>(
            h_c, cw3 + (long)l*2795520, P3, 256, 2730, 1024, 128);
        reduce_gated_k<<<2730, 256, 0, stream>>>(P, P3, 8, g_c, 698880);
        // w2: x += g @ cw2^T, K=2730, KS=22 (Kc=128)
        gemm_sk_k<<<dim3(16,4,22), 256, 0, stream>>>(
            g_c, cw2 + (long)l*2795520, P, 256, 1024, 2730, 128);
        reduce_plain_k<<<1024, 256, 0, stream>>>(P, 22, nullptr, x_c, x_c, 262144, 1024);
    }
    scatter_k<<<256, 256, 0, stream>>>(x_c, sidx, proc);

    // ---- Decoder k/v projections (fp32 split-K, before q-proj overwrites P region)
    gemm_sk_k<<<dim3(16,4,8), 256, 0, stream>>>(
        proc, dinw + 1048576, P, 256, 1024, 1024, 128);
    reduce_plain_k<<<1024, 256, 0, stream>>>(P, 8, dinb + 1024, nullptr, kkb, 262144, 1024);
    gemm_sk_k<<<dim3(16,4,8), 256, 0, stream>>>(
        proc, dinw + 2097152, P, 256, 1024, 1024, 128);
    reduce_plain_k<<<1024, 256, 0, stream>>>(P, 8, dinb + 2048, nullptr, vvb, 262144, 1024);

    // ---- Decoder big GEMMs (bf16 MFMA) ----
    // q = tok @ wq^T + bq
    mfma_gemm_k<<<dim3(8,64), 256, 0, stream>>>(tok_bf, wq_bf, dinb, nullptr, q_d, 1024, 1024);
    dec_attn_k<<<dim3(32,16,4), 256, 0, stream>>>(q_d, kkb, vvb, att_bf);
    // t1 = attn @ doutw^T + doutb + tok
    mfma_gemm_k<<<dim3(8,64), 256, 0, stream>>>(att_bf, wo_bf, doutb, tok, t1, 1024, 1024);
    // y1 = rms(t1)*dec_norm_w ; x2 = rms(y1)*dec_ffn_norm_w
    rms_k<float><<<8192, 256, 0, stream>>>(t1, dnw, y1);
    rms_k<bf16> <<<8192, 256, 0, stream>>>(y1, dfnw, x2_bf);
    // g = silu(x2@w1^T)*(x2@w3^T) -> g_d (bf16, N padded 2816)
    mfma_gated_k<<<dim3(22,64), 512, 0, stream>>>(x2_bf, w1_bf, w3_bf, g_d, 1024, 2816);
    // y = y1 + g@w2^T -> fp32 out
    mfma_gemm_k<<<dim3(8,64), 256, 0, stream>>>(g_d, w2_bf, nullptr, y1, out, 1024, 2816);
}

// Round 2
// 1319.222 us; speedup vs baseline: 1.1623x; 1.0650x over previous
//
#include <hip/hip_runtime.h>
#include <hip/hip_bf16.h>
#include <math.h>

typedef __hip_bfloat16 bf16;
typedef __bf16 bf16x8 __attribute__((ext_vector_type(8)));
typedef float f32x4 __attribute__((ext_vector_type(4)));
typedef unsigned short ushort_t;

// Problem constants: B=4, S=2048, H=1024, K=64, NH=16, d=64, L=2, FF=2730 (pad 2816), EPS=1e-6
// Round 6:
//  - MFMA kernels: BK 32->64 (halve barrier drains), XOR chunk-swizzled LDS
//    (linear gl2lds dest + pre-swizzled GLOBAL source + same XOR on ds_read:
//    chunkpos = row*8 + (plane ^ (row&7)) -> conflict-free b128 frag reads).
//  - casc_attn: pad LDS [64][65] (was 64-way conflicted on staging + Sc), 4-acc dots.
//  - dec_attn: 4-acc QK dots, float4 q loads.
//  - fused reduce+res+rms (cascade, 2x/layer), fused double-rms (decoder).
//  - vectorized cvt_pad stores, float4 gather/scatter.

__device__ __forceinline__ void  stf(float* p, long i, float v){ p[i] = v; }
__device__ __forceinline__ void  stf(bf16*  p, long i, float v){ p[i] = __float2bfloat16(v); }

#define AS1 __attribute__((address_space(1)))
#define AS3 __attribute__((address_space(3)))

__device__ __forceinline__ void gl2lds16(const void* g, void* l){
    __builtin_amdgcn_global_load_lds((const AS1 void*)g, (AS3 void*)l, 16, 0, 0);
}

// ---------------- fp32 -> bf16 conversion with optional zero-padding -------------
__global__ __launch_bounds__(256) void cvt_pad_k(const float* __restrict__ src,
                                                 bf16* __restrict__ dst,
                                                 int rows_in, int cols_in, int cols_out){
    int r = blockIdx.x;
    const float* s = src + (long)r*cols_in;
    bf16* d = dst + (long)r*cols_out;
    bool rowok = r < rows_in;
    for (int c8 = threadIdx.x*8; c8 < cols_out; c8 += 2048){
        __align__(16) bf16 u[8];
        #pragma unroll
        for (int e = 0; e < 8; e++){
            float v = (rowok && (c8+e) < cols_in) ? s[c8+e] : 0.f;
            u[e] = __float2bfloat16(v);
        }
        *reinterpret_cast<uint4*>(d + c8) = *reinterpret_cast<const uint4*>(u);
    }
}

// ---------------- MFMA GEMM: C(fp32) = A(bf16,MxKd) @ W(bf16,NxKd)^T (+bias)(+Res)
// BK=64, XOR chunk swizzle: LDS chunkpos = row*8 + (plane ^ (row&7)).
__global__ __launch_bounds__(256) void mfma_gemm_k(
    const bf16* __restrict__ A, const bf16* __restrict__ W,
    const float* __restrict__ bias, const float* __restrict__ Res,
    float* __restrict__ C, int N, int Kd)
{
    __shared__ __align__(16) ushort_t As[128*64];
    __shared__ __align__(16) ushort_t Bs[128*64];
    const int tid = threadIdx.x;
    const int lane = tid & 63, wave = tid >> 6;
    const int wm = wave >> 1, wn = wave & 1;
    const int kg = lane >> 4, ln = lane & 15;
    const long bm = (long)blockIdx.y * 128, bn = (long)blockIdx.x * 128;

    // staging: 1024 chunks of 16B; thread handles L = i*256+tid; linear LDS dest,
    // pre-swizzled global source plane sp = (L&7) ^ (row&7).
    const ushort_t* Ag[4]; const ushort_t* Wg[4];
    #pragma unroll
    for (int i = 0; i < 4; i++){
        int L = i*256 + tid;
        int row = L >> 3;
        int sp  = (L & 7) ^ (row & 7);
        Ag[i] = (const ushort_t*)A + (bm + row)*(long)Kd + sp*8;
        Wg[i] = (const ushort_t*)W + (bn + row)*(long)Kd + sp*8;
    }

    f32x4 acc[4][4] = {};
    for (int k0 = 0; k0 < Kd; k0 += 64){
        #pragma unroll
        for (int i = 0; i < 4; i++){
            gl2lds16(Ag[i], &As[i*2048 + tid*8]);
            gl2lds16(Wg[i], &Bs[i*2048 + tid*8]);
            Ag[i] += 64; Wg[i] += 64;
        }
        __syncthreads();
        #pragma unroll
        for (int s = 0; s < 2; s++){
            bf16x8 af[4], bfr[4];
            #pragma unroll
            for (int t = 0; t < 4; t++){
                int ra = wm*64 + t*16 + ln;
                int rb = wn*64 + t*16 + ln;
                af[t]  = *(const bf16x8*)&As[ra*64 + ((s*4+kg) ^ (ra&7))*8];
                bfr[t] = *(const bf16x8*)&Bs[rb*64 + ((s*4+kg) ^ (rb&7))*8];
            }
            #pragma unroll
            for (int i = 0; i < 4; i++)
                #pragma unroll
                for (int j = 0; j < 4; j++)
                    acc[i][j] = __builtin_amdgcn_mfma_f32_16x16x32_bf16(af[i], bfr[j], acc[i][j], 0, 0, 0);
        }
        __syncthreads();
    }
    #pragma unroll
    for (int i = 0; i < 4; i++){
        long gm0 = bm + wm*64 + i*16 + kg*4;
        #pragma unroll
        for (int j = 0; j < 4; j++){
            long gn = bn + wn*64 + j*16 + ln;
            float bv = bias ? bias[gn] : 0.f;
            #pragma unroll
            for (int r = 0; r < 4; r++){
                long gm = gm0 + r;
                float v = acc[i][j][r] + bv;
                if (Res) v += Res[gm*N + gn];
                C[gm*N + gn] = v;
            }
        }
    }
}

// ---------------- MFMA gated GEMM: C(bf16) = silu(A@W1^T) * (A@W3^T) -------------
// 8 waves, 128x128 tile, BK=64, swizzled LDS. LDS 48KB -> 3 blocks/CU.
__global__ __launch_bounds__(512, 4) void mfma_gated_k(
    const bf16* __restrict__ A, const bf16* __restrict__ W1,
    const bf16* __restrict__ W3, bf16* __restrict__ C, int Kd, int Nstride)
{
    __shared__ __align__(16) ushort_t As[128*64];
    __shared__ __align__(16) ushort_t B1s[128*64];
    __shared__ __align__(16) ushort_t B3s[128*64];
    const int tid = threadIdx.x;
    const int lane = tid & 63, wave = tid >> 6;   // 8 waves
    const int wm = wave >> 2, wn = wave & 3;      // 2 (row-halves) x 4 (col-quarters)
    const int kg = lane >> 4, ln = lane & 15;
    const long bm = (long)blockIdx.y * 128, bn = (long)blockIdx.x * 128;

    const ushort_t* Ag[2]; const ushort_t* W1g[2]; const ushort_t* W3g[2];
    #pragma unroll
    for (int i = 0; i < 2; i++){
        int L = i*512 + tid;
        int row = L >> 3;
        int sp  = (L & 7) ^ (row & 7);
        Ag[i]  = (const ushort_t*)A  + (bm + row)*(long)Kd + sp*8;
        W1g[i] = (const ushort_t*)W1 + (bn + row)*(long)Kd + sp*8;
        W3g[i] = (const ushort_t*)W3 + (bn + row)*(long)Kd + sp*8;
    }

    f32x4 acc1[4][2] = {};
    f32x4 acc3[4][2] = {};
    for (int k0 = 0; k0 < Kd; k0 += 64){
        #pragma unroll
        for (int i = 0; i < 2; i++){
            gl2lds16(Ag[i],  &As [i*4096 + tid*8]);
            gl2lds16(W1g[i], &B1s[i*4096 + tid*8]);
            gl2lds16(W3g[i], &B3s[i*4096 + tid*8]);
            Ag[i] += 64; W1g[i] += 64; W3g[i] += 64;
        }
        __syncthreads();
        #pragma unroll
        for (int s = 0; s < 2; s++){
            bf16x8 af[4], b1[2], b3[2];
            #pragma unroll
            for (int t = 0; t < 4; t++){
                int ra = wm*64 + t*16 + ln;
                af[t] = *(const bf16x8*)&As[ra*64 + ((s*4+kg) ^ (ra&7))*8];
            }
            #pragma unroll
            for (int j = 0; j < 2; j++){
                int rb = wn*32 + j*16 + ln;
                b1[j] = *(const bf16x8*)&B1s[rb*64 + ((s*4+kg) ^ (rb&7))*8];
                b3[j] = *(const bf16x8*)&B3s[rb*64 + ((s*4+kg) ^ (rb&7))*8];
            }
            #pragma unroll
            for (int i = 0; i < 4; i++)
                #pragma unroll
                for (int j = 0; j < 2; j++){
                    acc1[i][j] = __builtin_amdgcn_mfma_f32_16x16x32_bf16(af[i], b1[j], acc1[i][j], 0, 0, 0);
                    acc3[i][j] = __builtin_amdgcn_mfma_f32_16x16x32_bf16(af[i], b3[j], acc3[i][j], 0, 0, 0);
                }
        }
        __syncthreads();
    }
    #pragma unroll
    for (int i = 0; i < 4; i++){
        long gm0 = bm + wm*64 + i*16 + kg*4;
        #pragma unroll
        for (int j = 0; j < 2; j++){
            long gn = bn + wn*32 + j*16 + ln;
            #pragma unroll
            for (int r = 0; r < 4; r++){
                float x1 = acc1[i][j][r];
                float g  = x1 / (1.0f + expf(-x1));
                C[(gm0 + r)*Nstride + gn] = __float2bfloat16(g * acc3[i][j][r]);
            }
        }
    }
}

// ---------------- fp32 split-K GEMM: P[kz] = A(MxKd) @ W(NxKd)^T chunk -----------
__global__ __launch_bounds__(256) void gemm_sk_k(
    const float* __restrict__ A, const float* __restrict__ W,
    float* __restrict__ P, int M, int N, int Kd, int Kc)
{
    __shared__ float As[16][65];
    __shared__ float Ws[16][65];
    const int bm = blockIdx.y*64, bn = blockIdx.x*64;
    const int kz = blockIdx.z;
    const int kbeg = kz*Kc, kend = min(kbeg + Kc, Kd);
    const int tid = threadIdx.x;
    const int tx = tid & 15, ty = tid >> 4;
    float acc[4][4] = {};
    for (int k0 = kbeg; k0 < kend; k0 += 16){
        for (int e = tid; e < 1024; e += 256){
            int m = e >> 4, kk = e & 15;
            int gk = k0 + kk;
            int gm = bm + m;
            int gn = bn + m;
            As[kk][m] = (gm < M && gk < kend) ? A[(long)gm*Kd + gk] : 0.f;
            Ws[kk][m] = (gn < N && gk < kend) ? W[(long)gn*Kd + gk] : 0.f;
        }
        __syncthreads();
        #pragma unroll
        for (int kk = 0; kk < 16; kk++){
            float a[4], b[4];
            #pragma unroll
            for (int i = 0; i < 4; i++) a[i] = As[kk][ty*4+i];
            #pragma unroll
            for (int j = 0; j < 4; j++) b[j] = Ws[kk][tx*4+j];
            #pragma unroll
            for (int i = 0; i < 4; i++)
                #pragma unroll
                for (int j = 0; j < 4; j++)
                    acc[i][j] = fmaf(a[i], b[j], acc[i][j]);
        }
        __syncthreads();
    }
    float* Pz = P + (long)kz*M*N;
    #pragma unroll
    for (int i = 0; i < 4; i++){
        int m = bm + ty*4 + i;
        if (m >= M) continue;
        #pragma unroll
        for (int j = 0; j < 4; j++){
            int n = bn + tx*4 + j;
            if (n >= N) continue;
            Pz[(long)m*N + n] = acc[i][j];
        }
    }
}

// ---------------- reduce: C = sum_ks P (+bias)(+Res) ------------------------------
__global__ __launch_bounds__(256) void reduce_plain_k(
    const float* __restrict__ P, int KS, const float* __restrict__ bias,
    const float* __restrict__ Res, float* __restrict__ C, long MN, int N)
{
    long i = (long)blockIdx.x*256 + threadIdx.x;
    if (i >= MN) return;
    float s = 0.f;
    for (int k = 0; k < KS; k++) s += P[(long)k*MN + i];
    if (bias) s += bias[i % N];
    if (Res)  s += Res[i];
    C[i] = s;
}

// ---------------- reduce gated: C = silu(sum P1) * (sum P3) -----------------------
__global__ __launch_bounds__(256) void reduce_gated_k(
    const float* __restrict__ P1, const float* __restrict__ P3, int KS,
    float* __restrict__ C, long MN)
{
    long i = (long)blockIdx.x*256 + threadIdx.x;
    if (i >= MN) return;
    float s1 = 0.f, s3 = 0.f;
    for (int k = 0; k < KS; k++){ s1 += P1[(long)k*MN + i]; s3 += P3[(long)k*MN + i]; }
    float g = s1 / (1.0f + expf(-s1));
    C[i] = g * s3;
}

// ---------------- fused: x = sum_ks P + Res ; h = rms(x)*w  (row len 1024) -------
__global__ __launch_bounds__(256) void reduce_res_rms_k(
    const float* __restrict__ P, int KS, long MN,
    const float* __restrict__ Res, const float* __restrict__ w,
    float* __restrict__ xout, float* __restrict__ hout)
{
    long row = blockIdx.x;
    int tid = threadIdx.x;
    float v[4]; float ss = 0.f;
    #pragma unroll
    for (int j = 0; j < 4; j++){
        long i = row*1024 + tid + j*256;
        float s = Res[i];
        for (int k = 0; k < KS; k++) s += P[(long)k*MN + i];
        v[j] = s; ss += s*s;
    }
    #pragma unroll
    for (int off = 32; off; off >>= 1) ss += __shfl_down(ss, off, 64);
    __shared__ float red[4];
    __shared__ float scale_s;
    int wv = tid >> 6, ln = tid & 63;
    if (ln == 0) red[wv] = ss;
    __syncthreads();
    if (tid == 0)
        scale_s = rsqrtf((red[0]+red[1]+red[2]+red[3])*(1.0f/1024.f) + 1e-6f);
    __syncthreads();
    float sc = scale_s;
    #pragma unroll
    for (int j = 0; j < 4; j++){
        int c = tid + j*256;
        long i = row*1024 + c;
        xout[i] = v[j];
        hout[i] = v[j]*sc*w[c];
    }
}

// ---------------- stable descending argsort of chunk_weights (K=64) -------------
__global__ void sort_chunks_k(const float* __restrict__ w, int* __restrict__ sidx){
    int b = blockIdx.x, t = threadIdx.x;
    __shared__ float ws_[64];
    ws_[t] = w[b*64 + t];
    __syncthreads();
    float mine = ws_[t];
    int rank = 0;
    for (int j = 0; j < 64; j++){
        float wj = ws_[j];
        rank += (wj > mine) || (wj == mine && j < t);
    }
    sidx[b*64 + rank] = t;
}

__global__ void gather_k(const float* __restrict__ src, const int* __restrict__ sidx,
                         float* __restrict__ dst){
    int row = blockIdx.x; int b = row >> 6, r = row & 63;
    int sr = sidx[b*64 + r];
    const float4* s4 = (const float4*)(src + ((long)(b*64 + sr))*1024);
    float4* d4 = (float4*)(dst + (long)row*1024);
    d4[threadIdx.x] = s4[threadIdx.x];
}

__global__ void scatter_k(const float* __restrict__ x, const int* __restrict__ sidx,
                          float* __restrict__ proc){
    int row = blockIdx.x; int b = row >> 6, r = row & 63;
    int dr = sidx[b*64 + r];
    const float4* s4 = (const float4*)(x + (long)row*1024);
    float4* d4 = (float4*)(proc + ((long)(b*64 + dr))*1024);
    d4[threadIdx.x] = s4[threadIdx.x];
}

// ---------------- RMSNorm (row length fixed 1024) --------------------------------
template<typename TO>
__global__ __launch_bounds__(256) void rms_k(const float* __restrict__ x,
                                             const float* __restrict__ w,
                                             TO* __restrict__ o){
    long row = blockIdx.x;
    const float* xr = x + row*1024;
    float v[4]; float ss = 0.f;
    #pragma unroll
    for (int j = 0; j < 4; j++){ v[j] = xr[threadIdx.x + j*256]; ss += v[j]*v[j]; }
    #pragma unroll
    for (int off = 32; off; off >>= 1) ss += __shfl_down(ss, off, 64);
    __shared__ float red[4];
    __shared__ float scale_s;
    int wave = threadIdx.x >> 6, lane = threadIdx.x & 63;
    if (lane == 0) red[wave] = ss;
    __syncthreads();
    if (threadIdx.x == 0){
        float t = red[0] + red[1] + red[2] + red[3];
        scale_s = rsqrtf(t * (1.0f/1024.f) + 1e-6f);
    }
    __syncthreads();
    float sc = scale_s;
    #pragma unroll
    for (int j = 0; j < 4; j++){
        int i = threadIdx.x + j*256;
        stf(o, row*1024 + i, v[j] * sc * w[i]);
    }
}

// ---------------- fused double RMSNorm: y=rms(x)*w1 ; o2=rms(y)*w2 (bf16) --------
__global__ __launch_bounds__(256) void rms2_k(const float* __restrict__ x,
    const float* __restrict__ w1, const float* __restrict__ w2,
    float* __restrict__ y, bf16* __restrict__ o2)
{
    long row = blockIdx.x;
    const float* xr = x + row*1024;
    int tid = threadIdx.x;
    float v[4]; float ss = 0.f;
    #pragma unroll
    for (int j = 0; j < 4; j++){ v[j] = xr[tid + j*256]; ss += v[j]*v[j]; }
    #pragma unroll
    for (int off = 32; off; off >>= 1) ss += __shfl_down(ss, off, 64);
    __shared__ float redA[4], redB[4];
    __shared__ float sA, sB;
    int wv = tid >> 6, ln = tid & 63;
    if (ln == 0) redA[wv] = ss;
    __syncthreads();
    if (tid == 0) sA = rsqrtf((redA[0]+redA[1]+redA[2]+redA[3])*(1.0f/1024.f) + 1e-6f);
    __syncthreads();
    float sc1 = sA;
    float yv[4]; float ss2 = 0.f;
    #pragma unroll
    for (int j = 0; j < 4; j++){
        int c = tid + j*256;
        yv[j] = v[j]*sc1*w1[c];
        y[row*1024 + c] = yv[j];
        ss2 += yv[j]*yv[j];
    }
    #pragma unroll
    for (int off = 32; off; off >>= 1) ss2 += __shfl_down(ss2, off, 64);
    if (ln == 0) redB[wv] = ss2;
    __syncthreads();
    if (tid == 0) sB = rsqrtf((redB[0]+redB[1]+redB[2]+redB[3])*(1.0f/1024.f) + 1e-6f);
    __syncthreads();
    float sc2 = sB;
    #pragma unroll
    for (int j = 0; j < 4; j++){
        int c = tid + j*256;
        o2[row*1024 + c] = __float2bfloat16(yv[j]*sc2*w2[c]);
    }
}

// ---------------- Cascade causal self-attention (K=64, d=64, per (b,h)) ----------
// Padded LDS (was 64-way bank-conflicted), 4-partial-accumulator dots.
__global__ __launch_bounds__(64) void casc_attn_k(const float* __restrict__ qkv,
                                                  float* __restrict__ o){
    int b = blockIdx.x >> 4, h = blockIdx.x & 15;
    __shared__ float Ks[64][65], Vs[64][65], Sc[64][65];
    int t = threadIdx.x;
    const float* base = qkv + ((long)(b*64 + t))*3072 + h*64;
    float qr[64];
    #pragma unroll
    for (int i = 0; i < 64; i++){
        qr[i]    = base[i];
        Ks[t][i] = base[1024 + i];
        Vs[t][i] = base[2048 + i];
    }
    __syncthreads();
    float m = -1e30f;
    for (int j = 0; j < 64; j++){
        float d0=0.f,d1=0.f,d2=0.f,d3=0.f;
        #pragma unroll
        for (int i = 0; i < 64; i += 4){
            d0 = fmaf(qr[i],   Ks[j][i],   d0);
            d1 = fmaf(qr[i+1], Ks[j][i+1], d1);
            d2 = fmaf(qr[i+2], Ks[j][i+2], d2);
            d3 = fmaf(qr[i+3], Ks[j][i+3], d3);
        }
        float dot = ((d0+d1)+(d2+d3)) * 0.125f;
        Sc[t][j] = dot;
        if (j <= t) m = fmaxf(m, dot);
    }
    float l = 0.f;
    float p[64];
    #pragma unroll
    for (int j = 0; j < 64; j++){
        float e = (j <= t) ? expf(Sc[t][j] - m) : 0.f;
        p[j] = e; l += e;
    }
    float inv = 1.f / l;
    float* op = o + ((long)(b*64 + t))*1024 + h*64;
    for (int i = 0; i < 64; i++){
        float a0=0.f,a1=0.f,a2=0.f,a3=0.f;
        #pragma unroll
        for (int j = 0; j < 64; j += 4){
            a0 = fmaf(p[j],   Vs[j][i],   a0);
            a1 = fmaf(p[j+1], Vs[j+1][i], a1);
            a2 = fmaf(p[j+2], Vs[j+2][i], a2);
            a3 = fmaf(p[j+3], Vs[j+3][i], a3);
        }
        op[i] = ((a0+a1)+(a2+a3)) * inv;
    }
}

// ---------------- Decoder cross-attention -> bf16 output -------------------------
__global__ __launch_bounds__(256) void dec_attn_k(const float* __restrict__ q,
    const float* __restrict__ kk, const float* __restrict__ vv, bf16* __restrict__ o){
    int s0 = blockIdx.x*64, h = blockIdx.y, b = blockIdx.z;
    __shared__ float Ks[64][64], Vs[64][64], Sc[64][65];
    int tid = threadIdx.x;
    for (int e = tid; e < 4096; e += 256){
        int c = e >> 6, i = e & 63;
        Ks[c][i] = kk[((long)(b*64 + c))*1024 + h*64 + i];
        Vs[c][i] = vv[((long)(b*64 + c))*1024 + h*64 + i];
    }
    __syncthreads();
    int r = tid >> 2, seg = tid & 3;
    int s = s0 + r;
    float qr[64];
    const float4* qp4 = (const float4*)(q + ((long)(b*2048 + s))*1024 + h*64);
    #pragma unroll
    for (int j = 0; j < 16; j++){
        float4 t4 = qp4[j];
        qr[4*j] = t4.x; qr[4*j+1] = t4.y; qr[4*j+2] = t4.z; qr[4*j+3] = t4.w;
    }
    int cmax = s/32 + 1;
    for (int c = seg*16; c < seg*16 + 16; c++){
        float d0=0.f,d1=0.f,d2=0.f,d3=0.f;
        #pragma unroll
        for (int i = 0; i < 64; i += 4){
            d0 = fmaf(qr[i],   Ks[c][i],   d0);
            d1 = fmaf(qr[i+1], Ks[c][i+1], d1);
            d2 = fmaf(qr[i+2], Ks[c][i+2], d2);
            d3 = fmaf(qr[i+3], Ks[c][i+3], d3);
        }
        float dot = (d0+d1)+(d2+d3);
        Sc[r][c] = (c <= cmax) ? dot*0.125f : -1e30f;
    }
    __syncthreads();
    if (tid < 64){
        float m = -1e30f;
        for (int c = 0; c < 64; c++) m = fmaxf(m, Sc[tid][c]);
        float l = 0.f;
        for (int c = 0; c < 64; c++){ float e = expf(Sc[tid][c] - m); Sc[tid][c] = e; l += e; }
        float inv = 1.f / l;
        for (int c = 0; c < 64; c++) Sc[tid][c] *= inv;
    }
    __syncthreads();
    float accv[16] = {};
    for (int c = 0; c < 64; c++){
        float p = Sc[r][c];
        #pragma unroll
        for (int i = 0; i < 16; i++) accv[i] = fmaf(p, Vs[c][seg*16 + i], accv[i]);
    }
    bf16* op = o + ((long)(b*2048 + s))*1024 + h*64 + seg*16;
    #pragma unroll
    for (int i = 0; i < 16; i++) op[i] = __float2bfloat16(accv[i]);
}

// ---------------------------------------------------------------------------------
extern "C" void kernel_launch(void* const* d_in, const int* in_sizes, int n_in,
                              void* d_out, int out_size, void* d_ws, size_t ws_size,
                              hipStream_t stream)
{
    const float* tok   = (const float*)d_in[0];
    const float* crepr = (const float*)d_in[1];
    const float* cw    = (const float*)d_in[2];
    const float* n1    = (const float*)d_in[3];
    const float* cqkv  = (const float*)d_in[4];
    const float* co    = (const float*)d_in[5];
    const float* n2    = (const float*)d_in[6];
    const float* cw1   = (const float*)d_in[7];
    const float* cw2   = (const float*)d_in[8];
    const float* cw3   = (const float*)d_in[9];
    const float* dinw  = (const float*)d_in[10];
    const float* dinb  = (const float*)d_in[11];
    const float* doutw = (const float*)d_in[12];
    const float* doutb = (const float*)d_in[13];
    const float* dnw   = (const float*)d_in[14];
    const float* dfnw  = (const float*)d_in[15];
    const float* dw1   = (const float*)d_in[16];
    const float* dw2   = (const float*)d_in[17];
    const float* dw3   = (const float*)d_in[18];
    float* out = (float*)d_out;

    // Workspace layout (float units). Same total as before (~180 MB).
    float* F = (float*)d_ws;
    long off = 0;
    int*   sidx  = (int*)d_ws;        off += 1024;
    float* x_c   = F + off;           off += 262144;    // 256x1024
    float* h_c   = F + off;           off += 262144;
    float* qkv_c = F + off;           off += 786432;    // 256x3072
    float* o_c   = F + off;           off += 262144;
    float* g_c   = F + off;           off += 698880;    // 256x2730
    float* proc  = F + off;           off += 262144;
    float* kkb   = F + off;           off += 262144;
    float* vvb   = F + off;           off += 262144;
    float* q_d   = F + off;           off += 8388608;   // 8192x1024 fp32
    float* y1    = F + off;           off += 8388608;   // 8192x1024 fp32
    bf16*  tok_bf= (bf16*)(F + off);  off += 4194304;   // 8192x1024 bf16
    bf16*  att_bf= (bf16*)(F + off);  off += 4194304;   // 8192x1024 bf16
    bf16*  wq_bf = (bf16*)(F + off);  off += 524288;    // 1024x1024 bf16
    bf16*  wo_bf = (bf16*)(F + off);  off += 524288;
    bf16*  w1_bf = (bf16*)(F + off);  off += 1441792;   // 2816x1024 bf16
    bf16*  w3_bf = (bf16*)(F + off);  off += 1441792;
    bf16*  w2_bf = (bf16*)(F + off);  off += 1441792;   // 1024x2816 bf16
    float* t1    = F + off;
    bf16*  g_d   = (bf16*)(F + off);  off += 11534336;  // 8192x2816 bf16 (t1 overlays)
    bf16*  x2_bf = tok_bf;                              // reuse after q-proj

    // Split-K partial pool: aliases q_d..y1 (dead during cascade + k/v projections).
    float* P  = q_d;
    float* P3 = q_d + 5591040;

    // ---- bf16 conversions (decoder weights/activations) ----
    cvt_pad_k<<<8192, 256, 0, stream>>>(tok,   tok_bf, 8192, 1024, 1024);
    cvt_pad_k<<<1024, 256, 0, stream>>>(dinw,  wq_bf,  1024, 1024, 1024);
    cvt_pad_k<<<1024, 256, 0, stream>>>(doutw, wo_bf,  1024, 1024, 1024);
    cvt_pad_k<<<2816, 256, 0, stream>>>(dw1,   w1_bf,  2730, 1024, 1024);
    cvt_pad_k<<<2816, 256, 0, stream>>>(dw3,   w3_bf,  2730, 1024, 1024);
    cvt_pad_k<<<1024, 256, 0, stream>>>(dw2,   w2_bf,  1024, 2730, 2816);

    // ---- Cascade processor (fp32 split-K) ----
    sort_chunks_k<<<4, 64, 0, stream>>>(cw, sidx);
    gather_k<<<256, 256, 0, stream>>>(crepr, sidx, x_c);
    rms_k<float><<<256, 256, 0, stream>>>(x_c, n1, h_c);
    for (int l = 0; l < 2; l++){
        // qkv: 256x3072 = h @ cqkv^T, K=1024, KS=8
        gemm_sk_k<<<dim3(48,4,8), 256, 0, stream>>>(
            h_c, cqkv + (long)l*3145728, P, 256, 3072, 1024, 128);
        reduce_plain_k<<<3072, 256, 0, stream>>>(P, 8, nullptr, nullptr, qkv_c, 786432, 3072);
        casc_attn_k<<<64, 64, 0, stream>>>(qkv_c, o_c);
        // o-proj: x += o @ co^T; fused reduce+res+rms2 -> x_c, h_c
        gemm_sk_k<<<dim3(16,4,8), 256, 0, stream>>>(
            o_c, co + (long)l*1048576, P, 256, 1024, 1024, 128);
        reduce_res_rms_k<<<256, 256, 0, stream>>>(P, 8, 262144, x_c, n2 + l*1024, x_c, h_c);
        // gated FFN: P1 = h@w1^T, P3 = h@w3^T (N=2730, 43 n-tiles), KS=8
        gemm_sk_k<<<dim3(43,4,8), 256, 0, stream>>>(
            h_c, cw1 + (long)l*2795520, P,  256, 2730, 1024, 128);
        gemm_sk_k<<<dim3(43,4,8), 256, 0, stream>>>(
            h_c, cw3 + (long)l*2795520, P3, 256, 2730, 1024, 128);
        reduce_gated_k<<<2730, 256, 0, stream>>>(P, P3, 8, g_c, 698880);
        // w2: x += g @ cw2^T, K=2730, KS=22; fused reduce+res+rms1(next layer)
        gemm_sk_k<<<dim3(16,4,22), 256, 0, stream>>>(
            g_c, cw2 + (long)l*2795520, P, 256, 1024, 2730, 128);
        reduce_res_rms_k<<<256, 256, 0, stream>>>(P, 22, 262144, x_c, n1 + 1024, x_c, h_c);
    }
    scatter_k<<<256, 256, 0, stream>>>(x_c, sidx, proc);

    // ---- Decoder k/v projections (fp32 split-K, before q-proj overwrites P region)
    gemm_sk_k<<<dim3(16,4,8), 256, 0, stream>>>(
        proc, dinw + 1048576, P, 256, 1024, 1024, 128);
    reduce_plain_k<<<1024, 256, 0, stream>>>(P, 8, dinb + 1024, nullptr, kkb, 262144, 1024);
    gemm_sk_k<<<dim3(16,4,8), 256, 0, stream>>>(
        proc, dinw + 2097152, P, 256, 1024, 1024, 128);
    reduce_plain_k<<<1024, 256, 0, stream>>>(P, 8, dinb + 2048, nullptr, vvb, 262144, 1024);

    // ---- Decoder big GEMMs (bf16 MFMA) ----
    // q = tok @ wq^T + bq
    mfma_gemm_k<<<dim3(8,64), 256, 0, stream>>>(tok_bf, wq_bf, dinb, nullptr, q_d, 1024, 1024);
    dec_attn_k<<<dim3(32,16,4), 256, 0, stream>>>(q_d, kkb, vvb, att_bf);
    // t1 = attn @ doutw^T + doutb + tok
    mfma_gemm_k<<<dim3(8,64), 256, 0, stream>>>(att_bf, wo_bf, doutb, tok, t1, 1024, 1024);
    // y1 = rms(t1)*dnw ; x2 = rms(y1)*dfnw  (fused)
    rms2_k<<<8192, 256, 0, stream>>>(t1, dnw, dfnw, y1, x2_bf);
    // g = silu(x2@w1^T)*(x2@w3^T) -> g_d (bf16, N padded 2816)
    mfma_gated_k<<<dim3(22,64), 512, 0, stream>>>(x2_bf, w1_bf, w3_bf, g_d, 1024, 2816);
    // y = y1 + g@w2^T -> fp32 out
    mfma_gemm_k<<<dim3(8,64), 256, 0, stream>>>(g_d, w2_bf, nullptr, y1, out, 1024, 2816);
}

// Round 3
// 1264.343 us; speedup vs baseline: 1.2127x; 1.0434x over previous
//
#include <hip/hip_runtime.h>
#include <hip/hip_bf16.h>
#include <math.h>

typedef __hip_bfloat16 bf16;
typedef __bf16 bf16x8 __attribute__((ext_vector_type(8)));
typedef float f32x4 __attribute__((ext_vector_type(4)));
typedef unsigned short ushort_t;

// Problem constants: B=4, S=2048, H=1024, K=64, NH=16, d=64, L=2, FF=2730 (pad 2816), EPS=1e-6
// Round 7:
//  - dec_attn rewritten as MFMA flash-style kernel (was LDS-issue-bound VALU with
//    2.54e7 bank-conflict cycles, 106us). K/V^T staged bf16 + chunk-XOR swizzle,
//    in-register softmax via shfl_xor over 16-lane group, P via per-wave LDS.
//  - q-projection now emits bf16 (mfma_gemm_k templated on output type).
//  - cascade FFN: w1/w3 split-K GEMMs fused into one dual kernel (shared A staging).

__device__ __forceinline__ void  stf(float* p, long i, float v){ p[i] = v; }
__device__ __forceinline__ void  stf(bf16*  p, long i, float v){ p[i] = __float2bfloat16(v); }

#define AS1 __attribute__((address_space(1)))
#define AS3 __attribute__((address_space(3)))

__device__ __forceinline__ void gl2lds16(const void* g, void* l){
    __builtin_amdgcn_global_load_lds((const AS1 void*)g, (AS3 void*)l, 16, 0, 0);
}

// ---------------- fp32 -> bf16 conversion with optional zero-padding -------------
__global__ __launch_bounds__(256) void cvt_pad_k(const float* __restrict__ src,
                                                 bf16* __restrict__ dst,
                                                 int rows_in, int cols_in, int cols_out){
    int r = blockIdx.x;
    const float* s = src + (long)r*cols_in;
    bf16* d = dst + (long)r*cols_out;
    bool rowok = r < rows_in;
    for (int c8 = threadIdx.x*8; c8 < cols_out; c8 += 2048){
        __align__(16) bf16 u[8];
        #pragma unroll
        for (int e = 0; e < 8; e++){
            float v = (rowok && (c8+e) < cols_in) ? s[c8+e] : 0.f;
            u[e] = __float2bfloat16(v);
        }
        *reinterpret_cast<uint4*>(d + c8) = *reinterpret_cast<const uint4*>(u);
    }
}

// ---------------- MFMA GEMM: C(TO) = A(bf16,MxKd) @ W(bf16,NxKd)^T (+bias)(+Res)
// BK=64, XOR chunk swizzle: LDS chunkpos = row*8 + (plane ^ (row&7)).
template<typename TO>
__global__ __launch_bounds__(256) void mfma_gemm_k(
    const bf16* __restrict__ A, const bf16* __restrict__ W,
    const float* __restrict__ bias, const float* __restrict__ Res,
    TO* __restrict__ C, int N, int Kd)
{
    __shared__ __align__(16) ushort_t As[128*64];
    __shared__ __align__(16) ushort_t Bs[128*64];
    const int tid = threadIdx.x;
    const int lane = tid & 63, wave = tid >> 6;
    const int wm = wave >> 1, wn = wave & 1;
    const int kg = lane >> 4, ln = lane & 15;
    const long bm = (long)blockIdx.y * 128, bn = (long)blockIdx.x * 128;

    const ushort_t* Ag[4]; const ushort_t* Wg[4];
    #pragma unroll
    for (int i = 0; i < 4; i++){
        int L = i*256 + tid;
        int row = L >> 3;
        int sp  = (L & 7) ^ (row & 7);
        Ag[i] = (const ushort_t*)A + (bm + row)*(long)Kd + sp*8;
        Wg[i] = (const ushort_t*)W + (bn + row)*(long)Kd + sp*8;
    }

    f32x4 acc[4][4] = {};
    for (int k0 = 0; k0 < Kd; k0 += 64){
        #pragma unroll
        for (int i = 0; i < 4; i++){
            gl2lds16(Ag[i], &As[i*2048 + tid*8]);
            gl2lds16(Wg[i], &Bs[i*2048 + tid*8]);
            Ag[i] += 64; Wg[i] += 64;
        }
        __syncthreads();
        #pragma unroll
        for (int s = 0; s < 2; s++){
            bf16x8 af[4], bfr[4];
            #pragma unroll
            for (int t = 0; t < 4; t++){
                int ra = wm*64 + t*16 + ln;
                int rb = wn*64 + t*16 + ln;
                af[t]  = *(const bf16x8*)&As[ra*64 + ((s*4+kg) ^ (ra&7))*8];
                bfr[t] = *(const bf16x8*)&Bs[rb*64 + ((s*4+kg) ^ (rb&7))*8];
            }
            #pragma unroll
            for (int i = 0; i < 4; i++)
                #pragma unroll
                for (int j = 0; j < 4; j++)
                    acc[i][j] = __builtin_amdgcn_mfma_f32_16x16x32_bf16(af[i], bfr[j], acc[i][j], 0, 0, 0);
        }
        __syncthreads();
    }
    #pragma unroll
    for (int i = 0; i < 4; i++){
        long gm0 = bm + wm*64 + i*16 + kg*4;
        #pragma unroll
        for (int j = 0; j < 4; j++){
            long gn = bn + wn*64 + j*16 + ln;
            float bv = bias ? bias[gn] : 0.f;
            #pragma unroll
            for (int r = 0; r < 4; r++){
                long gm = gm0 + r;
                float v = acc[i][j][r] + bv;
                if (Res) v += Res[gm*N + gn];
                stf(C, gm*N + gn, v);
            }
        }
    }
}

// ---------------- MFMA gated GEMM: C(bf16) = silu(A@W1^T) * (A@W3^T) -------------
__global__ __launch_bounds__(512, 4) void mfma_gated_k(
    const bf16* __restrict__ A, const bf16* __restrict__ W1,
    const bf16* __restrict__ W3, bf16* __restrict__ C, int Kd, int Nstride)
{
    __shared__ __align__(16) ushort_t As[128*64];
    __shared__ __align__(16) ushort_t B1s[128*64];
    __shared__ __align__(16) ushort_t B3s[128*64];
    const int tid = threadIdx.x;
    const int lane = tid & 63, wave = tid >> 6;   // 8 waves
    const int wm = wave >> 2, wn = wave & 3;      // 2 (row-halves) x 4 (col-quarters)
    const int kg = lane >> 4, ln = lane & 15;
    const long bm = (long)blockIdx.y * 128, bn = (long)blockIdx.x * 128;

    const ushort_t* Ag[2]; const ushort_t* W1g[2]; const ushort_t* W3g[2];
    #pragma unroll
    for (int i = 0; i < 2; i++){
        int L = i*512 + tid;
        int row = L >> 3;
        int sp  = (L & 7) ^ (row & 7);
        Ag[i]  = (const ushort_t*)A  + (bm + row)*(long)Kd + sp*8;
        W1g[i] = (const ushort_t*)W1 + (bn + row)*(long)Kd + sp*8;
        W3g[i] = (const ushort_t*)W3 + (bn + row)*(long)Kd + sp*8;
    }

    f32x4 acc1[4][2] = {};
    f32x4 acc3[4][2] = {};
    for (int k0 = 0; k0 < Kd; k0 += 64){
        #pragma unroll
        for (int i = 0; i < 2; i++){
            gl2lds16(Ag[i],  &As [i*4096 + tid*8]);
            gl2lds16(W1g[i], &B1s[i*4096 + tid*8]);
            gl2lds16(W3g[i], &B3s[i*4096 + tid*8]);
            Ag[i] += 64; W1g[i] += 64; W3g[i] += 64;
        }
        __syncthreads();
        #pragma unroll
        for (int s = 0; s < 2; s++){
            bf16x8 af[4], b1[2], b3[2];
            #pragma unroll
            for (int t = 0; t < 4; t++){
                int ra = wm*64 + t*16 + ln;
                af[t] = *(const bf16x8*)&As[ra*64 + ((s*4+kg) ^ (ra&7))*8];
            }
            #pragma unroll
            for (int j = 0; j < 2; j++){
                int rb = wn*32 + j*16 + ln;
                b1[j] = *(const bf16x8*)&B1s[rb*64 + ((s*4+kg) ^ (rb&7))*8];
                b3[j] = *(const bf16x8*)&B3s[rb*64 + ((s*4+kg) ^ (rb&7))*8];
            }
            #pragma unroll
            for (int i = 0; i < 4; i++)
                #pragma unroll
                for (int j = 0; j < 2; j++){
                    acc1[i][j] = __builtin_amdgcn_mfma_f32_16x16x32_bf16(af[i], b1[j], acc1[i][j], 0, 0, 0);
                    acc3[i][j] = __builtin_amdgcn_mfma_f32_16x16x32_bf16(af[i], b3[j], acc3[i][j], 0, 0, 0);
                }
        }
        __syncthreads();
    }
    #pragma unroll
    for (int i = 0; i < 4; i++){
        long gm0 = bm + wm*64 + i*16 + kg*4;
        #pragma unroll
        for (int j = 0; j < 2; j++){
            long gn = bn + wn*32 + j*16 + ln;
            #pragma unroll
            for (int r = 0; r < 4; r++){
                float x1 = acc1[i][j][r];
                float g  = x1 / (1.0f + expf(-x1));
                C[(gm0 + r)*Nstride + gn] = __float2bfloat16(g * acc3[i][j][r]);
            }
        }
    }
}

// ---------------- fp32 split-K GEMM: P[kz] = A(MxKd) @ W(NxKd)^T chunk -----------
__global__ __launch_bounds__(256) void gemm_sk_k(
    const float* __restrict__ A, const float* __restrict__ W,
    float* __restrict__ P, int M, int N, int Kd, int Kc)
{
    __shared__ float As[16][65];
    __shared__ float Ws[16][65];
    const int bm = blockIdx.y*64, bn = blockIdx.x*64;
    const int kz = blockIdx.z;
    const int kbeg = kz*Kc, kend = min(kbeg + Kc, Kd);
    const int tid = threadIdx.x;
    const int tx = tid & 15, ty = tid >> 4;
    float acc[4][4] = {};
    for (int k0 = kbeg; k0 < kend; k0 += 16){
        for (int e = tid; e < 1024; e += 256){
            int m = e >> 4, kk = e & 15;
            int gk = k0 + kk;
            int gm = bm + m;
            int gn = bn + m;
            As[kk][m] = (gm < M && gk < kend) ? A[(long)gm*Kd + gk] : 0.f;
            Ws[kk][m] = (gn < N && gk < kend) ? W[(long)gn*Kd + gk] : 0.f;
        }
        __syncthreads();
        #pragma unroll
        for (int kk = 0; kk < 16; kk++){
            float a[4], b[4];
            #pragma unroll
            for (int i = 0; i < 4; i++) a[i] = As[kk][ty*4+i];
            #pragma unroll
            for (int j = 0; j < 4; j++) b[j] = Ws[kk][tx*4+j];
            #pragma unroll
            for (int i = 0; i < 4; i++)
                #pragma unroll
                for (int j = 0; j < 4; j++)
                    acc[i][j] = fmaf(a[i], b[j], acc[i][j]);
        }
        __syncthreads();
    }
    float* Pz = P + (long)kz*M*N;
    #pragma unroll
    for (int i = 0; i < 4; i++){
        int m = bm + ty*4 + i;
        if (m >= M) continue;
        #pragma unroll
        for (int j = 0; j < 4; j++){
            int n = bn + tx*4 + j;
            if (n >= N) continue;
            Pz[(long)m*N + n] = acc[i][j];
        }
    }
}

// ---------------- dual fp32 split-K GEMM: P1/P3 = A @ W1^T / A @ W3^T ------------
__global__ __launch_bounds__(256) void gemm_sk_dual_k(
    const float* __restrict__ A, const float* __restrict__ W1,
    const float* __restrict__ W3, float* __restrict__ P1, float* __restrict__ P3,
    int M, int N, int Kd, int Kc)
{
    __shared__ float As[16][65];
    __shared__ float W1s[16][65];
    __shared__ float W3s[16][65];
    const int bm = blockIdx.y*64, bn = blockIdx.x*64;
    const int kz = blockIdx.z;
    const int kbeg = kz*Kc, kend = min(kbeg + Kc, Kd);
    const int tid = threadIdx.x;
    const int tx = tid & 15, ty = tid >> 4;
    float acc1[4][4] = {};
    float acc3[4][4] = {};
    for (int k0 = kbeg; k0 < kend; k0 += 16){
        for (int e = tid; e < 1024; e += 256){
            int m = e >> 4, kk = e & 15;
            int gk = k0 + kk;
            int gm = bm + m;
            int gn = bn + m;
            As[kk][m]  = (gm < M && gk < kend) ? A[(long)gm*Kd + gk]  : 0.f;
            W1s[kk][m] = (gn < N && gk < kend) ? W1[(long)gn*Kd + gk] : 0.f;
            W3s[kk][m] = (gn < N && gk < kend) ? W3[(long)gn*Kd + gk] : 0.f;
        }
        __syncthreads();
        #pragma unroll
        for (int kk = 0; kk < 16; kk++){
            float a[4], b1[4], b3[4];
            #pragma unroll
            for (int i = 0; i < 4; i++) a[i]  = As[kk][ty*4+i];
            #pragma unroll
            for (int j = 0; j < 4; j++){ b1[j] = W1s[kk][tx*4+j]; b3[j] = W3s[kk][tx*4+j]; }
            #pragma unroll
            for (int i = 0; i < 4; i++)
                #pragma unroll
                for (int j = 0; j < 4; j++){
                    acc1[i][j] = fmaf(a[i], b1[j], acc1[i][j]);
                    acc3[i][j] = fmaf(a[i], b3[j], acc3[i][j]);
                }
        }
        __syncthreads();
    }
    float* P1z = P1 + (long)kz*M*N;
    float* P3z = P3 + (long)kz*M*N;
    #pragma unroll
    for (int i = 0; i < 4; i++){
        int m = bm + ty*4 + i;
        if (m >= M) continue;
        #pragma unroll
        for (int j = 0; j < 4; j++){
            int n = bn + tx*4 + j;
            if (n >= N) continue;
            P1z[(long)m*N + n] = acc1[i][j];
            P3z[(long)m*N + n] = acc3[i][j];
        }
    }
}

// ---------------- reduce: C = sum_ks P (+bias)(+Res) ------------------------------
__global__ __launch_bounds__(256) void reduce_plain_k(
    const float* __restrict__ P, int KS, const float* __restrict__ bias,
    const float* __restrict__ Res, float* __restrict__ C, long MN, int N)
{
    long i = (long)blockIdx.x*256 + threadIdx.x;
    if (i >= MN) return;
    float s = 0.f;
    for (int k = 0; k < KS; k++) s += P[(long)k*MN + i];
    if (bias) s += bias[i % N];
    if (Res)  s += Res[i];
    C[i] = s;
}

// ---------------- reduce gated: C = silu(sum P1) * (sum P3) -----------------------
__global__ __launch_bounds__(256) void reduce_gated_k(
    const float* __restrict__ P1, const float* __restrict__ P3, int KS,
    float* __restrict__ C, long MN)
{
    long i = (long)blockIdx.x*256 + threadIdx.x;
    if (i >= MN) return;
    float s1 = 0.f, s3 = 0.f;
    for (int k = 0; k < KS; k++){ s1 += P1[(long)k*MN + i]; s3 += P3[(long)k*MN + i]; }
    float g = s1 / (1.0f + expf(-s1));
    C[i] = g * s3;
}

// ---------------- fused: x = sum_ks P + Res ; h = rms(x)*w  (row len 1024) -------
__global__ __launch_bounds__(256) void reduce_res_rms_k(
    const float* __restrict__ P, int KS, long MN,
    const float* __restrict__ Res, const float* __restrict__ w,
    float* __restrict__ xout, float* __restrict__ hout)
{
    long row = blockIdx.x;
    int tid = threadIdx.x;
    float v[4]; float ss = 0.f;
    #pragma unroll
    for (int j = 0; j < 4; j++){
        long i = row*1024 + tid + j*256;
        float s = Res[i];
        for (int k = 0; k < KS; k++) s += P[(long)k*MN + i];
        v[j] = s; ss += s*s;
    }
    #pragma unroll
    for (int off = 32; off; off >>= 1) ss += __shfl_down(ss, off, 64);
    __shared__ float red[4];
    __shared__ float scale_s;
    int wv = tid >> 6, ln = tid & 63;
    if (ln == 0) red[wv] = ss;
    __syncthreads();
    if (tid == 0)
        scale_s = rsqrtf((red[0]+red[1]+red[2]+red[3])*(1.0f/1024.f) + 1e-6f);
    __syncthreads();
    float sc = scale_s;
    #pragma unroll
    for (int j = 0; j < 4; j++){
        int c = tid + j*256;
        long i = row*1024 + c;
        xout[i] = v[j];
        hout[i] = v[j]*sc*w[c];
    }
}

// ---------------- stable descending argsort of chunk_weights (K=64) -------------
__global__ void sort_chunks_k(const float* __restrict__ w, int* __restrict__ sidx){
    int b = blockIdx.x, t = threadIdx.x;
    __shared__ float ws_[64];
    ws_[t] = w[b*64 + t];
    __syncthreads();
    float mine = ws_[t];
    int rank = 0;
    for (int j = 0; j < 64; j++){
        float wj = ws_[j];
        rank += (wj > mine) || (wj == mine && j < t);
    }
    sidx[b*64 + rank] = t;
}

__global__ void gather_k(const float* __restrict__ src, const int* __restrict__ sidx,
                         float* __restrict__ dst){
    int row = blockIdx.x; int b = row >> 6, r = row & 63;
    int sr = sidx[b*64 + r];
    const float4* s4 = (const float4*)(src + ((long)(b*64 + sr))*1024);
    float4* d4 = (float4*)(dst + (long)row*1024);
    d4[threadIdx.x] = s4[threadIdx.x];
}

__global__ void scatter_k(const float* __restrict__ x, const int* __restrict__ sidx,
                          float* __restrict__ proc){
    int row = blockIdx.x; int b = row >> 6, r = row & 63;
    int dr = sidx[b*64 + r];
    const float4* s4 = (const float4*)(x + (long)row*1024);
    float4* d4 = (float4*)(proc + ((long)(b*64 + dr))*1024);
    d4[threadIdx.x] = s4[threadIdx.x];
}

// ---------------- RMSNorm (row length fixed 1024) --------------------------------
template<typename TO>
__global__ __launch_bounds__(256) void rms_k(const float* __restrict__ x,
                                             const float* __restrict__ w,
                                             TO* __restrict__ o){
    long row = blockIdx.x;
    const float* xr = x + row*1024;
    float v[4]; float ss = 0.f;
    #pragma unroll
    for (int j = 0; j < 4; j++){ v[j] = xr[threadIdx.x + j*256]; ss += v[j]*v[j]; }
    #pragma unroll
    for (int off = 32; off; off >>= 1) ss += __shfl_down(ss, off, 64);
    __shared__ float red[4];
    __shared__ float scale_s;
    int wave = threadIdx.x >> 6, lane = threadIdx.x & 63;
    if (lane == 0) red[wave] = ss;
    __syncthreads();
    if (threadIdx.x == 0){
        float t = red[0] + red[1] + red[2] + red[3];
        scale_s = rsqrtf(t * (1.0f/1024.f) + 1e-6f);
    }
    __syncthreads();
    float sc = scale_s;
    #pragma unroll
    for (int j = 0; j < 4; j++){
        int i = threadIdx.x + j*256;
        stf(o, row*1024 + i, v[j] * sc * w[i]);
    }
}

// ---------------- fused double RMSNorm: y=rms(x)*w1 ; o2=rms(y)*w2 (bf16) --------
__global__ __launch_bounds__(256) void rms2_k(const float* __restrict__ x,
    const float* __restrict__ w1, const float* __restrict__ w2,
    float* __restrict__ y, bf16* __restrict__ o2)
{
    long row = blockIdx.x;
    const float* xr = x + row*1024;
    int tid = threadIdx.x;
    float v[4]; float ss = 0.f;
    #pragma unroll
    for (int j = 0; j < 4; j++){ v[j] = xr[tid + j*256]; ss += v[j]*v[j]; }
    #pragma unroll
    for (int off = 32; off; off >>= 1) ss += __shfl_down(ss, off, 64);
    __shared__ float redA[4], redB[4];
    __shared__ float sA, sB;
    int wv = tid >> 6, ln = tid & 63;
    if (ln == 0) redA[wv] = ss;
    __syncthreads();
    if (tid == 0) sA = rsqrtf((redA[0]+redA[1]+redA[2]+redA[3])*(1.0f/1024.f) + 1e-6f);
    __syncthreads();
    float sc1 = sA;
    float yv[4]; float ss2 = 0.f;
    #pragma unroll
    for (int j = 0; j < 4; j++){
        int c = tid + j*256;
        yv[j] = v[j]*sc1*w1[c];
        y[row*1024 + c] = yv[j];
        ss2 += yv[j]*yv[j];
    }
    #pragma unroll
    for (int off = 32; off; off >>= 1) ss2 += __shfl_down(ss2, off, 64);
    if (ln == 0) redB[wv] = ss2;
    __syncthreads();
    if (tid == 0) sB = rsqrtf((redB[0]+redB[1]+redB[2]+redB[3])*(1.0f/1024.f) + 1e-6f);
    __syncthreads();
    float sc2 = sB;
    #pragma unroll
    for (int j = 0; j < 4; j++){
        int c = tid + j*256;
        o2[row*1024 + c] = __float2bfloat16(yv[j]*sc2*w2[c]);
    }
}

// ---------------- Cascade causal self-attention (K=64, d=64, per (b,h)) ----------
__global__ __launch_bounds__(64) void casc_attn_k(const float* __restrict__ qkv,
                                                  float* __restrict__ o){
    int b = blockIdx.x >> 4, h = blockIdx.x & 15;
    __shared__ float Ks[64][65], Vs[64][65], Sc[64][65];
    int t = threadIdx.x;
    const float* base = qkv + ((long)(b*64 + t))*3072 + h*64;
    float qr[64];
    #pragma unroll
    for (int i = 0; i < 64; i++){
        qr[i]    = base[i];
        Ks[t][i] = base[1024 + i];
        Vs[t][i] = base[2048 + i];
    }
    __syncthreads();
    float m = -1e30f;
    for (int j = 0; j < 64; j++){
        float d0=0.f,d1=0.f,d2=0.f,d3=0.f;
        #pragma unroll
        for (int i = 0; i < 64; i += 4){
            d0 = fmaf(qr[i],   Ks[j][i],   d0);
            d1 = fmaf(qr[i+1], Ks[j][i+1], d1);
            d2 = fmaf(qr[i+2], Ks[j][i+2], d2);
            d3 = fmaf(qr[i+3], Ks[j][i+3], d3);
        }
        float dot = ((d0+d1)+(d2+d3)) * 0.125f;
        Sc[t][j] = dot;
        if (j <= t) m = fmaxf(m, dot);
    }
    float l = 0.f;
    float p[64];
    #pragma unroll
    for (int j = 0; j < 64; j++){
        float e = (j <= t) ? expf(Sc[t][j] - m) : 0.f;
        p[j] = e; l += e;
    }
    float inv = 1.f / l;
    float* op = o + ((long)(b*64 + t))*1024 + h*64;
    for (int i = 0; i < 64; i++){
        float a0=0.f,a1=0.f,a2=0.f,a3=0.f;
        #pragma unroll
        for (int j = 0; j < 64; j += 4){
            a0 = fmaf(p[j],   Vs[j][i],   a0);
            a1 = fmaf(p[j+1], Vs[j+1][i], a1);
            a2 = fmaf(p[j+2], Vs[j+2][i], a2);
            a3 = fmaf(p[j+3], Vs[j+3][i], a3);
        }
        op[i] = ((a0+a1)+(a2+a3)) * inv;
    }
}

// ---------------- Decoder cross-attention (MFMA) -> bf16 output ------------------
// 4 waves x 64 s-rows = 256 rows/block. K/V^T bf16 in LDS (chunk-XOR swizzled).
// scores fp32 in regs; in-register softmax (shfl_xor over 16-lane group); P via
// per-wave swizzled LDS; PV MFMA; divide by row-sum at epilogue.
__global__ __launch_bounds__(256) void dec_attn_mfma_k(
    const bf16* __restrict__ q,   // (B*2048, 1024) bf16
    const float* __restrict__ kk, // (B*64, 1024) fp32 (bias applied)
    const float* __restrict__ vv,
    bf16* __restrict__ o)         // (B*2048, 1024) bf16
{
    const int s0 = blockIdx.x*256, h = blockIdx.y, b = blockIdx.z;
    __shared__ __align__(16) bf16 Ksm[64*64];
    __shared__ __align__(16) bf16 Vtm[64*64];
    __shared__ __align__(16) bf16 Pm[4][64*64];
    const int tid = threadIdx.x;
    const int lane = tid & 63, wv = tid >> 6;
    const int kg = lane >> 4, ln = lane & 15;

    // stage K: row c (kv idx), d-chunk cc -> chunk cc^(c&7)
    for (int e = tid; e < 512; e += 256){
        int c = e >> 3, cc = e & 7;
        const float* src = kk + ((long)(b*64 + c))*1024 + h*64 + cc*8;
        __align__(16) bf16 u[8];
        #pragma unroll
        for (int x = 0; x < 8; x++) u[x] = __float2bfloat16(src[x]);
        *reinterpret_cast<uint4*>(&Ksm[c*64 + ((cc ^ (c&7))<<3)]) = *reinterpret_cast<const uint4*>(u);
    }
    // stage V^T: Vtm[d][c], c-chunk (c>>3)^(d&7)
    for (int e = tid; e < 4096; e += 256){
        int c = e >> 6, d0 = e & 63;
        float v = vv[((long)(b*64 + c))*1024 + h*64 + d0];
        int cc = c >> 3, ci = c & 7;
        Vtm[d0*64 + (((cc ^ (d0&7))<<3) + ci)] = __float2bfloat16(v);
    }

    // load Q fragments from global (rows s0 + wv*64 + i*16 + ln)
    bf16x8 qf[4][2];
    #pragma unroll
    for (int i = 0; i < 4; i++)
        #pragma unroll
        for (int s = 0; s < 2; s++){
            long row = (long)b*2048 + s0 + wv*64 + i*16 + ln;
            qf[i][s] = *(const bf16x8*)&q[row*1024 + h*64 + s*32 + kg*8];
        }
    __syncthreads();

    // QK^T
    f32x4 sacc[4][4] = {};
    #pragma unroll
    for (int s = 0; s < 2; s++){
        bf16x8 kf[4];
        #pragma unroll
        for (int j = 0; j < 4; j++){
            int rb = j*16 + ln;
            kf[j] = *(const bf16x8*)&Ksm[rb*64 + (((s*4+kg) ^ (rb&7))<<3)];
        }
        #pragma unroll
        for (int i = 0; i < 4; i++)
            #pragma unroll
            for (int j = 0; j < 4; j++)
                sacc[i][j] = __builtin_amdgcn_mfma_f32_16x16x32_bf16(qf[i][s], kf[j], sacc[i][j], 0, 0, 0);
    }

    // mask + softmax (lane holds rows kg*4+r of tile i, col j*16+ln)
    float l_val[4][4];
    #pragma unroll
    for (int i = 0; i < 4; i++){
        #pragma unroll
        for (int r = 0; r < 4; r++){
            int s_idx = s0 + wv*64 + i*16 + kg*4 + r;
            int cmax = (s_idx >> 5) + 1;
            float mx = -1e30f;
            #pragma unroll
            for (int j = 0; j < 4; j++){
                int c = j*16 + ln;
                float sc = sacc[i][j][r] * 0.125f;
                sc = (c <= cmax) ? sc : -1e30f;
                sacc[i][j][r] = sc;
                mx = fmaxf(mx, sc);
            }
            #pragma unroll
            for (int off = 1; off < 16; off <<= 1) mx = fmaxf(mx, __shfl_xor(mx, off, 64));
            float sum = 0.f;
            #pragma unroll
            for (int j = 0; j < 4; j++){
                float e = __expf(sacc[i][j][r] - mx);
                sacc[i][j][r] = e;
                sum += e;
            }
            #pragma unroll
            for (int off = 1; off < 16; off <<= 1) sum += __shfl_xor(sum, off, 64);
            l_val[i][r] = sum;
        }
    }

    // write P to per-wave LDS (bf16, chunk-XOR swizzle for A-frag reads)
    bf16* Pw = &Pm[wv][0];
    #pragma unroll
    for (int i = 0; i < 4; i++)
        #pragma unroll
        for (int r = 0; r < 4; r++){
            int prow = i*16 + kg*4 + r;
            #pragma unroll
            for (int j = 0; j < 4; j++){
                int pcol = j*16 + ln;
                int cc = pcol >> 3, ci = pcol & 7;
                Pw[prow*64 + (((cc ^ (prow&7))<<3) + ci)] = __float2bfloat16(sacc[i][j][r]);
            }
        }

    // PV (per-wave P; compiler inserts lgkmcnt before dependent ds_read)
    f32x4 oacc[4][4] = {};
    #pragma unroll
    for (int s = 0; s < 2; s++){
        bf16x8 pf[4], vf[4];
        #pragma unroll
        for (int i = 0; i < 4; i++){
            int ra = i*16 + ln;
            pf[i] = *(const bf16x8*)&Pw[ra*64 + (((s*4+kg) ^ (ra&7))<<3)];
        }
        #pragma unroll
        for (int j = 0; j < 4; j++){
            int rb = j*16 + ln;
            vf[j] = *(const bf16x8*)&Vtm[rb*64 + (((s*4+kg) ^ (rb&7))<<3)];
        }
        #pragma unroll
        for (int i = 0; i < 4; i++)
            #pragma unroll
            for (int j = 0; j < 4; j++)
                oacc[i][j] = __builtin_amdgcn_mfma_f32_16x16x32_bf16(pf[i], vf[j], oacc[i][j], 0, 0, 0);
    }

    // epilogue: divide by row-sum, store bf16
    #pragma unroll
    for (int i = 0; i < 4; i++){
        #pragma unroll
        for (int r = 0; r < 4; r++){
            float invl = 1.f / l_val[i][r];
            long row = (long)b*2048 + s0 + wv*64 + i*16 + kg*4 + r;
            #pragma unroll
            for (int j = 0; j < 4; j++){
                long col = h*64 + j*16 + ln;
                o[row*1024 + col] = __float2bfloat16(oacc[i][j][r] * invl);
            }
        }
    }
}

// ---------------------------------------------------------------------------------
extern "C" void kernel_launch(void* const* d_in, const int* in_sizes, int n_in,
                              void* d_out, int out_size, void* d_ws, size_t ws_size,
                              hipStream_t stream)
{
    const float* tok   = (const float*)d_in[0];
    const float* crepr = (const float*)d_in[1];
    const float* cw    = (const float*)d_in[2];
    const float* n1    = (const float*)d_in[3];
    const float* cqkv  = (const float*)d_in[4];
    const float* co    = (const float*)d_in[5];
    const float* n2    = (const float*)d_in[6];
    const float* cw1   = (const float*)d_in[7];
    const float* cw2   = (const float*)d_in[8];
    const float* cw3   = (const float*)d_in[9];
    const float* dinw  = (const float*)d_in[10];
    const float* dinb  = (const float*)d_in[11];
    const float* doutw = (const float*)d_in[12];
    const float* doutb = (const float*)d_in[13];
    const float* dnw   = (const float*)d_in[14];
    const float* dfnw  = (const float*)d_in[15];
    const float* dw1   = (const float*)d_in[16];
    const float* dw2   = (const float*)d_in[17];
    const float* dw3   = (const float*)d_in[18];
    float* out = (float*)d_out;

    // Workspace layout (float units). Same total as before (~180 MB).
    float* F = (float*)d_ws;
    long off = 0;
    int*   sidx  = (int*)d_ws;        off += 1024;
    float* x_c   = F + off;           off += 262144;    // 256x1024
    float* h_c   = F + off;           off += 262144;
    float* qkv_c = F + off;           off += 786432;    // 256x3072
    float* o_c   = F + off;           off += 262144;
    float* g_c   = F + off;           off += 698880;    // 256x2730
    float* proc  = F + off;           off += 262144;
    float* kkb   = F + off;           off += 262144;
    float* vvb   = F + off;           off += 262144;
    float* q_d   = F + off;           off += 8388608;   // q bf16 (8192x1024) lives here
    float* y1    = F + off;           off += 8388608;   // 8192x1024 fp32
    bf16*  tok_bf= (bf16*)(F + off);  off += 4194304;   // 8192x1024 bf16
    bf16*  att_bf= (bf16*)(F + off);  off += 4194304;   // 8192x1024 bf16
    bf16*  wq_bf = (bf16*)(F + off);  off += 524288;    // 1024x1024 bf16
    bf16*  wo_bf = (bf16*)(F + off);  off += 524288;
    bf16*  w1_bf = (bf16*)(F + off);  off += 1441792;   // 2816x1024 bf16
    bf16*  w3_bf = (bf16*)(F + off);  off += 1441792;
    bf16*  w2_bf = (bf16*)(F + off);  off += 1441792;   // 1024x2816 bf16
    float* t1    = F + off;
    bf16*  g_d   = (bf16*)(F + off);  off += 11534336;  // 8192x2816 bf16 (t1 overlays)
    bf16*  x2_bf = tok_bf;                              // reuse after q-proj
    bf16*  q_bf  = (bf16*)q_d;                          // q-proj bf16 output

    // Split-K partial pool: aliases q_d..y1 (dead during cascade + k/v projections).
    float* P  = q_d;
    float* P3 = q_d + 5591040;

    // ---- bf16 conversions (decoder weights/activations) ----
    cvt_pad_k<<<8192, 256, 0, stream>>>(tok,   tok_bf, 8192, 1024, 1024);
    cvt_pad_k<<<1024, 256, 0, stream>>>(dinw,  wq_bf,  1024, 1024, 1024);
    cvt_pad_k<<<1024, 256, 0, stream>>>(doutw, wo_bf,  1024, 1024, 1024);
    cvt_pad_k<<<2816, 256, 0, stream>>>(dw1,   w1_bf,  2730, 1024, 1024);
    cvt_pad_k<<<2816, 256, 0, stream>>>(dw3,   w3_bf,  2730, 1024, 1024);
    cvt_pad_k<<<1024, 256, 0, stream>>>(dw2,   w2_bf,  1024, 2730, 2816);

    // ---- Cascade processor (fp32 split-K) ----
    sort_chunks_k<<<4, 64, 0, stream>>>(cw, sidx);
    gather_k<<<256, 256, 0, stream>>>(crepr, sidx, x_c);
    rms_k<float><<<256, 256, 0, stream>>>(x_c, n1, h_c);
    for (int l = 0; l < 2; l++){
        // qkv: 256x3072 = h @ cqkv^T, K=1024, KS=8
        gemm_sk_k<<<dim3(48,4,8), 256, 0, stream>>>(
            h_c, cqkv + (long)l*3145728, P, 256, 3072, 1024, 128);
        reduce_plain_k<<<3072, 256, 0, stream>>>(P, 8, nullptr, nullptr, qkv_c, 786432, 3072);
        casc_attn_k<<<64, 64, 0, stream>>>(qkv_c, o_c);
        // o-proj: x += o @ co^T; fused reduce+res+rms2 -> x_c, h_c
        gemm_sk_k<<<dim3(16,4,8), 256, 0, stream>>>(
            o_c, co + (long)l*1048576, P, 256, 1024, 1024, 128);
        reduce_res_rms_k<<<256, 256, 0, stream>>>(P, 8, 262144, x_c, n2 + l*1024, x_c, h_c);
        // gated FFN: P1 = h@w1^T, P3 = h@w3^T in one pass (shared A staging)
        gemm_sk_dual_k<<<dim3(43,4,8), 256, 0, stream>>>(
            h_c, cw1 + (long)l*2795520, cw3 + (long)l*2795520, P, P3, 256, 2730, 1024, 128);
        reduce_gated_k<<<2730, 256, 0, stream>>>(P, P3, 8, g_c, 698880);
        // w2: x += g @ cw2^T, K=2730, KS=22; fused reduce+res+rms1(next layer)
        gemm_sk_k<<<dim3(16,4,22), 256, 0, stream>>>(
            g_c, cw2 + (long)l*2795520, P, 256, 1024, 2730, 128);
        reduce_res_rms_k<<<256, 256, 0, stream>>>(P, 22, 262144, x_c, n1 + 1024, x_c, h_c);
    }
    scatter_k<<<256, 256, 0, stream>>>(x_c, sidx, proc);

    // ---- Decoder k/v projections (fp32 split-K, before q-proj overwrites P region)
    gemm_sk_k<<<dim3(16,4,8), 256, 0, stream>>>(
        proc, dinw + 1048576, P, 256, 1024, 1024, 128);
    reduce_plain_k<<<1024, 256, 0, stream>>>(P, 8, dinb + 1024, nullptr, kkb, 262144, 1024);
    gemm_sk_k<<<dim3(16,4,8), 256, 0, stream>>>(
        proc, dinw + 2097152, P, 256, 1024, 1024, 128);
    reduce_plain_k<<<1024, 256, 0, stream>>>(P, 8, dinb + 2048, nullptr, vvb, 262144, 1024);

    // ---- Decoder big GEMMs (bf16 MFMA) ----
    // q = tok @ wq^T + bq  (bf16 out)
    mfma_gemm_k<bf16><<<dim3(8,64), 256, 0, stream>>>(tok_bf, wq_bf, dinb, nullptr, q_bf, 1024, 1024);
    dec_attn_mfma_k<<<dim3(8,16,4), 256, 0, stream>>>(q_bf, kkb, vvb, att_bf);
    // t1 = attn @ doutw^T + doutb + tok
    mfma_gemm_k<float><<<dim3(8,64), 256, 0, stream>>>(att_bf, wo_bf, doutb, tok, t1, 1024, 1024);
    // y1 = rms(t1)*dnw ; x2 = rms(y1)*dfnw  (fused)
    rms2_k<<<8192, 256, 0, stream>>>(t1, dnw, dfnw, y1, x2_bf);
    // g = silu(x2@w1^T)*(x2@w3^T) -> g_d (bf16, N padded 2816)
    mfma_gated_k<<<dim3(22,64), 512, 0, stream>>>(x2_bf, w1_bf, w3_bf, g_d, 1024, 2816);
    // y = y1 + g@w2^T -> fp32 out
    mfma_gemm_k<float><<<dim3(8,64), 256, 0, stream>>>(g_d, w2_bf, nullptr, y1, out, 1024, 2816);
}

// Round 5
// 971.332 us; speedup vs baseline: 1.5786x; 1.3017x over previous
//
#include <hip/hip_runtime.h>
#include <hip/hip_bf16.h>
#include <math.h>

typedef __hip_bfloat16 bf16;
typedef __bf16 bf16x8 __attribute__((ext_vector_type(8)));
typedef float f32x4 __attribute__((ext_vector_type(4)));
typedef unsigned short ushort_t;

// Problem constants: B=4, S=2048, H=1024, K=64, NH=16, d=64, L=2, FF=2730 (pad 2816), EPS=1e-6
// Round 9 = Round 8 + fix: v-projection weight offset was fp32-unit 2097152 applied
// to a bf16 pointer (pointed past wkv_bf into tok_bf -> absmax 7.14). Correct bf16
// offset is 1048576 (row 1024 of the 2048x1024 wkv block).
// Cascade + k/v projections: bf16 MFMA split-K (mfma_sk_k, 128x128, BK=64,
// chunk-XOR swizzle, fp32 partials + reduce kernels). Residual x_c stays fp32.

__device__ __forceinline__ void  stf(float* p, long i, float v){ p[i] = v; }
__device__ __forceinline__ void  stf(bf16*  p, long i, float v){ p[i] = __float2bfloat16(v); }

#define AS1 __attribute__((address_space(1)))
#define AS3 __attribute__((address_space(3)))

__device__ __forceinline__ void gl2lds16(const void* g, void* l){
    __builtin_amdgcn_global_load_lds((const AS1 void*)g, (AS3 void*)l, 16, 0, 0);
}

// ---------------- fp32 -> bf16 conversion with optional zero-padding -------------
__global__ __launch_bounds__(256) void cvt_pad_k(const float* __restrict__ src,
                                                 bf16* __restrict__ dst,
                                                 int rows_in, int cols_in, int cols_out){
    int r = blockIdx.x;
    const float* s = src + (long)r*cols_in;
    bf16* d = dst + (long)r*cols_out;
    bool rowok = r < rows_in;
    for (int c8 = threadIdx.x*8; c8 < cols_out; c8 += 2048){
        __align__(16) bf16 u[8];
        #pragma unroll
        for (int e = 0; e < 8; e++){
            float v = (rowok && (c8+e) < cols_in) ? s[c8+e] : 0.f;
            u[e] = __float2bfloat16(v);
        }
        *reinterpret_cast<uint4*>(d + c8) = *reinterpret_cast<const uint4*>(u);
    }
}

// ---------------- MFMA GEMM: C(TO) = A(bf16,MxKd) @ W(bf16,NxKd)^T (+bias)(+Res)
// BK=64, XOR chunk swizzle: LDS chunkpos = row*8 + (plane ^ (row&7)).
template<typename TO>
__global__ __launch_bounds__(256) void mfma_gemm_k(
    const bf16* __restrict__ A, const bf16* __restrict__ W,
    const float* __restrict__ bias, const float* __restrict__ Res,
    TO* __restrict__ C, int N, int Kd)
{
    __shared__ __align__(16) ushort_t As[128*64];
    __shared__ __align__(16) ushort_t Bs[128*64];
    const int tid = threadIdx.x;
    const int lane = tid & 63, wave = tid >> 6;
    const int wm = wave >> 1, wn = wave & 1;
    const int kg = lane >> 4, ln = lane & 15;
    const long bm = (long)blockIdx.y * 128, bn = (long)blockIdx.x * 128;

    const ushort_t* Ag[4]; const ushort_t* Wg[4];
    #pragma unroll
    for (int i = 0; i < 4; i++){
        int L = i*256 + tid;
        int row = L >> 3;
        int sp  = (L & 7) ^ (row & 7);
        Ag[i] = (const ushort_t*)A + (bm + row)*(long)Kd + sp*8;
        Wg[i] = (const ushort_t*)W + (bn + row)*(long)Kd + sp*8;
    }

    f32x4 acc[4][4] = {};
    for (int k0 = 0; k0 < Kd; k0 += 64){
        #pragma unroll
        for (int i = 0; i < 4; i++){
            gl2lds16(Ag[i], &As[i*2048 + tid*8]);
            gl2lds16(Wg[i], &Bs[i*2048 + tid*8]);
            Ag[i] += 64; Wg[i] += 64;
        }
        __syncthreads();
        #pragma unroll
        for (int s = 0; s < 2; s++){
            bf16x8 af[4], bfr[4];
            #pragma unroll
            for (int t = 0; t < 4; t++){
                int ra = wm*64 + t*16 + ln;
                int rb = wn*64 + t*16 + ln;
                af[t]  = *(const bf16x8*)&As[ra*64 + ((s*4+kg) ^ (ra&7))*8];
                bfr[t] = *(const bf16x8*)&Bs[rb*64 + ((s*4+kg) ^ (rb&7))*8];
            }
            #pragma unroll
            for (int i = 0; i < 4; i++)
                #pragma unroll
                for (int j = 0; j < 4; j++)
                    acc[i][j] = __builtin_amdgcn_mfma_f32_16x16x32_bf16(af[i], bfr[j], acc[i][j], 0, 0, 0);
        }
        __syncthreads();
    }
    #pragma unroll
    for (int i = 0; i < 4; i++){
        long gm0 = bm + wm*64 + i*16 + kg*4;
        #pragma unroll
        for (int j = 0; j < 4; j++){
            long gn = bn + wn*64 + j*16 + ln;
            float bv = bias ? bias[gn] : 0.f;
            #pragma unroll
            for (int r = 0; r < 4; r++){
                long gm = gm0 + r;
                float v = acc[i][j][r] + bv;
                if (Res) v += Res[gm*N + gn];
                stf(C, gm*N + gn, v);
            }
        }
    }
}

// ---------------- MFMA split-K GEMM: P[kz] = A(bf16) @ W(bf16)^T chunk ----------
// 128x128 tile, BK=64, chunk-XOR swizzle; M = gridDim.y*128; fp32 partials.
__global__ __launch_bounds__(256) void mfma_sk_k(
    const bf16* __restrict__ A, const bf16* __restrict__ W,
    float* __restrict__ P, int N, int Kstride, int Kc)
{
    __shared__ __align__(16) ushort_t As[128*64];
    __shared__ __align__(16) ushort_t Bs[128*64];
    const int tid = threadIdx.x;
    const int lane = tid & 63, wave = tid >> 6;
    const int wm = wave >> 1, wn = wave & 1;
    const int kg = lane >> 4, ln = lane & 15;
    const long bm = (long)blockIdx.y * 128, bn = (long)blockIdx.x * 128;
    const int kbeg = blockIdx.z * Kc;

    const ushort_t* Ag[4]; const ushort_t* Wg[4];
    #pragma unroll
    for (int i = 0; i < 4; i++){
        int L = i*256 + tid;
        int row = L >> 3;
        int sp  = (L & 7) ^ (row & 7);
        Ag[i] = (const ushort_t*)A + (bm + row)*(long)Kstride + kbeg + sp*8;
        Wg[i] = (const ushort_t*)W + (bn + row)*(long)Kstride + kbeg + sp*8;
    }

    f32x4 acc[4][4] = {};
    for (int k0 = 0; k0 < Kc; k0 += 64){
        #pragma unroll
        for (int i = 0; i < 4; i++){
            gl2lds16(Ag[i], &As[i*2048 + tid*8]);
            gl2lds16(Wg[i], &Bs[i*2048 + tid*8]);
            Ag[i] += 64; Wg[i] += 64;
        }
        __syncthreads();
        #pragma unroll
        for (int s = 0; s < 2; s++){
            bf16x8 af[4], bfr[4];
            #pragma unroll
            for (int t = 0; t < 4; t++){
                int ra = wm*64 + t*16 + ln;
                int rb = wn*64 + t*16 + ln;
                af[t]  = *(const bf16x8*)&As[ra*64 + ((s*4+kg) ^ (ra&7))*8];
                bfr[t] = *(const bf16x8*)&Bs[rb*64 + ((s*4+kg) ^ (rb&7))*8];
            }
            #pragma unroll
            for (int i = 0; i < 4; i++)
                #pragma unroll
                for (int j = 0; j < 4; j++)
                    acc[i][j] = __builtin_amdgcn_mfma_f32_16x16x32_bf16(af[i], bfr[j], acc[i][j], 0, 0, 0);
        }
        __syncthreads();
    }
    const long Mtot = (long)gridDim.y * 128;
    float* Pz = P + (long)blockIdx.z * Mtot * N;
    #pragma unroll
    for (int i = 0; i < 4; i++){
        long gm0 = bm + wm*64 + i*16 + kg*4;
        #pragma unroll
        for (int j = 0; j < 4; j++){
            long gn = bn + wn*64 + j*16 + ln;
            #pragma unroll
            for (int r = 0; r < 4; r++)
                Pz[(gm0 + r)*N + gn] = acc[i][j][r];
        }
    }
}

// ---------------- MFMA gated GEMM: C(bf16) = silu(A@W1^T) * (A@W3^T) -------------
__global__ __launch_bounds__(512, 4) void mfma_gated_k(
    const bf16* __restrict__ A, const bf16* __restrict__ W1,
    const bf16* __restrict__ W3, bf16* __restrict__ C, int Kd, int Nstride)
{
    __shared__ __align__(16) ushort_t As[128*64];
    __shared__ __align__(16) ushort_t B1s[128*64];
    __shared__ __align__(16) ushort_t B3s[128*64];
    const int tid = threadIdx.x;
    const int lane = tid & 63, wave = tid >> 6;   // 8 waves
    const int wm = wave >> 2, wn = wave & 3;      // 2 (row-halves) x 4 (col-quarters)
    const int kg = lane >> 4, ln = lane & 15;
    const long bm = (long)blockIdx.y * 128, bn = (long)blockIdx.x * 128;

    const ushort_t* Ag[2]; const ushort_t* W1g[2]; const ushort_t* W3g[2];
    #pragma unroll
    for (int i = 0; i < 2; i++){
        int L = i*512 + tid;
        int row = L >> 3;
        int sp  = (L & 7) ^ (row & 7);
        Ag[i]  = (const ushort_t*)A  + (bm + row)*(long)Kd + sp*8;
        W1g[i] = (const ushort_t*)W1 + (bn + row)*(long)Kd + sp*8;
        W3g[i] = (const ushort_t*)W3 + (bn + row)*(long)Kd + sp*8;
    }

    f32x4 acc1[4][2] = {};
    f32x4 acc3[4][2] = {};
    for (int k0 = 0; k0 < Kd; k0 += 64){
        #pragma unroll
        for (int i = 0; i < 2; i++){
            gl2lds16(Ag[i],  &As [i*4096 + tid*8]);
            gl2lds16(W1g[i], &B1s[i*4096 + tid*8]);
            gl2lds16(W3g[i], &B3s[i*4096 + tid*8]);
            Ag[i] += 64; W1g[i] += 64; W3g[i] += 64;
        }
        __syncthreads();
        #pragma unroll
        for (int s = 0; s < 2; s++){
            bf16x8 af[4], b1[2], b3[2];
            #pragma unroll
            for (int t = 0; t < 4; t++){
                int ra = wm*64 + t*16 + ln;
                af[t] = *(const bf16x8*)&As[ra*64 + ((s*4+kg) ^ (ra&7))*8];
            }
            #pragma unroll
            for (int j = 0; j < 2; j++){
                int rb = wn*32 + j*16 + ln;
                b1[j] = *(const bf16x8*)&B1s[rb*64 + ((s*4+kg) ^ (rb&7))*8];
                b3[j] = *(const bf16x8*)&B3s[rb*64 + ((s*4+kg) ^ (rb&7))*8];
            }
            #pragma unroll
            for (int i = 0; i < 4; i++)
                #pragma unroll
                for (int j = 0; j < 2; j++){
                    acc1[i][j] = __builtin_amdgcn_mfma_f32_16x16x32_bf16(af[i], b1[j], acc1[i][j], 0, 0, 0);
                    acc3[i][j] = __builtin_amdgcn_mfma_f32_16x16x32_bf16(af[i], b3[j], acc3[i][j], 0, 0, 0);
                }
        }
        __syncthreads();
    }
    #pragma unroll
    for (int i = 0; i < 4; i++){
        long gm0 = bm + wm*64 + i*16 + kg*4;
        #pragma unroll
        for (int j = 0; j < 2; j++){
            long gn = bn + wn*32 + j*16 + ln;
            #pragma unroll
            for (int r = 0; r < 4; r++){
                float x1 = acc1[i][j][r];
                float g  = x1 / (1.0f + expf(-x1));
                C[(gm0 + r)*Nstride + gn] = __float2bfloat16(g * acc3[i][j][r]);
            }
        }
    }
}

// ---------------- reduce: C = sum_ks P (+bias)(+Res) ------------------------------
__global__ __launch_bounds__(256) void reduce_plain_k(
    const float* __restrict__ P, int KS, const float* __restrict__ bias,
    const float* __restrict__ Res, float* __restrict__ C, long MN, int N)
{
    long i = (long)blockIdx.x*256 + threadIdx.x;
    if (i >= MN) return;
    float s = 0.f;
    for (int k = 0; k < KS; k++) s += P[(long)k*MN + i];
    if (bias) s += bias[i % N];
    if (Res)  s += Res[i];
    C[i] = s;
}

// ---------------- reduce gated -> bf16: C = silu(sum P1) * (sum P3) ---------------
__global__ __launch_bounds__(256) void reduce_gated_bf_k(
    const float* __restrict__ P1, const float* __restrict__ P3, int KS,
    bf16* __restrict__ C, long MN)
{
    long i = (long)blockIdx.x*256 + threadIdx.x;
    if (i >= MN) return;
    float s1 = 0.f, s3 = 0.f;
    for (int k = 0; k < KS; k++){ s1 += P1[(long)k*MN + i]; s3 += P3[(long)k*MN + i]; }
    float g = s1 / (1.0f + expf(-s1));
    C[i] = __float2bfloat16(g * s3);
}

// ---------------- fused: x = sum_ks P + Res ; h = rms(x)*w (bf16 out) ------------
__global__ __launch_bounds__(256) void reduce_res_rms_k(
    const float* __restrict__ P, int KS, long MN,
    const float* __restrict__ Res, const float* __restrict__ w,
    float* __restrict__ xout, bf16* __restrict__ hout)
{
    long row = blockIdx.x;
    int tid = threadIdx.x;
    float v[4]; float ss = 0.f;
    #pragma unroll
    for (int j = 0; j < 4; j++){
        long i = row*1024 + tid + j*256;
        float s = Res[i];
        for (int k = 0; k < KS; k++) s += P[(long)k*MN + i];
        v[j] = s; ss += s*s;
    }
    #pragma unroll
    for (int off = 32; off; off >>= 1) ss += __shfl_down(ss, off, 64);
    __shared__ float red[4];
    __shared__ float scale_s;
    int wv = tid >> 6, ln = tid & 63;
    if (ln == 0) red[wv] = ss;
    __syncthreads();
    if (tid == 0)
        scale_s = rsqrtf((red[0]+red[1]+red[2]+red[3])*(1.0f/1024.f) + 1e-6f);
    __syncthreads();
    float sc = scale_s;
    #pragma unroll
    for (int j = 0; j < 4; j++){
        int c = tid + j*256;
        long i = row*1024 + c;
        xout[i] = v[j];
        hout[i] = __float2bfloat16(v[j]*sc*w[c]);
    }
}

// ---------------- stable descending argsort of chunk_weights (K=64) -------------
__global__ void sort_chunks_k(const float* __restrict__ w, int* __restrict__ sidx){
    int b = blockIdx.x, t = threadIdx.x;
    __shared__ float ws_[64];
    ws_[t] = w[b*64 + t];
    __syncthreads();
    float mine = ws_[t];
    int rank = 0;
    for (int j = 0; j < 64; j++){
        float wj = ws_[j];
        rank += (wj > mine) || (wj == mine && j < t);
    }
    sidx[b*64 + rank] = t;
}

__global__ void gather_k(const float* __restrict__ src, const int* __restrict__ sidx,
                         float* __restrict__ dst){
    int row = blockIdx.x; int b = row >> 6, r = row & 63;
    int sr = sidx[b*64 + r];
    const float4* s4 = (const float4*)(src + ((long)(b*64 + sr))*1024);
    float4* d4 = (float4*)(dst + (long)row*1024);
    d4[threadIdx.x] = s4[threadIdx.x];
}

// scatter + fp32->bf16 (proc consumed only by bf16 MFMA k/v projections)
__global__ void scatter_bf_k(const float* __restrict__ x, const int* __restrict__ sidx,
                             bf16* __restrict__ proc){
    int row = blockIdx.x; int b = row >> 6, r = row & 63;
    int dr = sidx[b*64 + r];
    float4 v = ((const float4*)(x + (long)row*1024))[threadIdx.x];
    __align__(8) bf16 u[4];
    u[0] = __float2bfloat16(v.x); u[1] = __float2bfloat16(v.y);
    u[2] = __float2bfloat16(v.z); u[3] = __float2bfloat16(v.w);
    *reinterpret_cast<uint2*>(proc + ((long)(b*64 + dr))*1024 + threadIdx.x*4)
        = *reinterpret_cast<const uint2*>(u);
}

// ---------------- RMSNorm (row length fixed 1024) --------------------------------
template<typename TO>
__global__ __launch_bounds__(256) void rms_k(const float* __restrict__ x,
                                             const float* __restrict__ w,
                                             TO* __restrict__ o){
    long row = blockIdx.x;
    const float* xr = x + row*1024;
    float v[4]; float ss = 0.f;
    #pragma unroll
    for (int j = 0; j < 4; j++){ v[j] = xr[threadIdx.x + j*256]; ss += v[j]*v[j]; }
    #pragma unroll
    for (int off = 32; off; off >>= 1) ss += __shfl_down(ss, off, 64);
    __shared__ float red[4];
    __shared__ float scale_s;
    int wave = threadIdx.x >> 6, lane = threadIdx.x & 63;
    if (lane == 0) red[wave] = ss;
    __syncthreads();
    if (threadIdx.x == 0){
        float t = red[0] + red[1] + red[2] + red[3];
        scale_s = rsqrtf(t * (1.0f/1024.f) + 1e-6f);
    }
    __syncthreads();
    float sc = scale_s;
    #pragma unroll
    for (int j = 0; j < 4; j++){
        int i = threadIdx.x + j*256;
        stf(o, row*1024 + i, v[j] * sc * w[i]);
    }
}

// ---------------- fused double RMSNorm: y=rms(x)*w1 ; o2=rms(y)*w2 (bf16) --------
__global__ __launch_bounds__(256) void rms2_k(const float* __restrict__ x,
    const float* __restrict__ w1, const float* __restrict__ w2,
    float* __restrict__ y, bf16* __restrict__ o2)
{
    long row = blockIdx.x;
    const float* xr = x + row*1024;
    int tid = threadIdx.x;
    float v[4]; float ss = 0.f;
    #pragma unroll
    for (int j = 0; j < 4; j++){ v[j] = xr[tid + j*256]; ss += v[j]*v[j]; }
    #pragma unroll
    for (int off = 32; off; off >>= 1) ss += __shfl_down(ss, off, 64);
    __shared__ float redA[4], redB[4];
    __shared__ float sA, sB;
    int wv = tid >> 6, ln = tid & 63;
    if (ln == 0) redA[wv] = ss;
    __syncthreads();
    if (tid == 0) sA = rsqrtf((redA[0]+redA[1]+redA[2]+redA[3])*(1.0f/1024.f) + 1e-6f);
    __syncthreads();
    float sc1 = sA;
    float yv[4]; float ss2 = 0.f;
    #pragma unroll
    for (int j = 0; j < 4; j++){
        int c = tid + j*256;
        yv[j] = v[j]*sc1*w1[c];
        y[row*1024 + c] = yv[j];
        ss2 += yv[j]*yv[j];
    }
    #pragma unroll
    for (int off = 32; off; off >>= 1) ss2 += __shfl_down(ss2, off, 64);
    if (ln == 0) redB[wv] = ss2;
    __syncthreads();
    if (tid == 0) sB = rsqrtf((redB[0]+redB[1]+redB[2]+redB[3])*(1.0f/1024.f) + 1e-6f);
    __syncthreads();
    float sc2 = sB;
    #pragma unroll
    for (int j = 0; j < 4; j++){
        int c = tid + j*256;
        o2[row*1024 + c] = __float2bfloat16(yv[j]*sc2*w2[c]);
    }
}

// ---------------- Cascade causal self-attention (K=64, d=64, per (b,h)) ----------
__global__ __launch_bounds__(64) void casc_attn_k(const float* __restrict__ qkv,
                                                  bf16* __restrict__ o){
    int b = blockIdx.x >> 4, h = blockIdx.x & 15;
    __shared__ float Ks[64][65], Vs[64][65], Sc[64][65];
    int t = threadIdx.x;
    const float* base = qkv + ((long)(b*64 + t))*3072 + h*64;
    float qr[64];
    #pragma unroll
    for (int i = 0; i < 64; i++){
        qr[i]    = base[i];
        Ks[t][i] = base[1024 + i];
        Vs[t][i] = base[2048 + i];
    }
    __syncthreads();
    float m = -1e30f;
    for (int j = 0; j < 64; j++){
        float d0=0.f,d1=0.f,d2=0.f,d3=0.f;
        #pragma unroll
        for (int i = 0; i < 64; i += 4){
            d0 = fmaf(qr[i],   Ks[j][i],   d0);
            d1 = fmaf(qr[i+1], Ks[j][i+1], d1);
            d2 = fmaf(qr[i+2], Ks[j][i+2], d2);
            d3 = fmaf(qr[i+3], Ks[j][i+3], d3);
        }
        float dot = ((d0+d1)+(d2+d3)) * 0.125f;
        Sc[t][j] = dot;
        if (j <= t) m = fmaxf(m, dot);
    }
    float l = 0.f;
    float p[64];
    #pragma unroll
    for (int j = 0; j < 64; j++){
        float e = (j <= t) ? expf(Sc[t][j] - m) : 0.f;
        p[j] = e; l += e;
    }
    float inv = 1.f / l;
    bf16* op = o + ((long)(b*64 + t))*1024 + h*64;
    for (int i = 0; i < 64; i++){
        float a0=0.f,a1=0.f,a2=0.f,a3=0.f;
        #pragma unroll
        for (int j = 0; j < 64; j += 4){
            a0 = fmaf(p[j],   Vs[j][i],   a0);
            a1 = fmaf(p[j+1], Vs[j+1][i], a1);
            a2 = fmaf(p[j+2], Vs[j+2][i], a2);
            a3 = fmaf(p[j+3], Vs[j+3][i], a3);
        }
        op[i] = __float2bfloat16(((a0+a1)+(a2+a3)) * inv);
    }
}

// ---------------- Decoder cross-attention (MFMA) -> bf16 output ------------------
__global__ __launch_bounds__(256) void dec_attn_mfma_k(
    const bf16* __restrict__ q,   // (B*2048, 1024) bf16
    const float* __restrict__ kk, // (B*64, 1024) fp32 (bias applied)
    const float* __restrict__ vv,
    bf16* __restrict__ o)         // (B*2048, 1024) bf16
{
    const int s0 = blockIdx.x*256, h = blockIdx.y, b = blockIdx.z;
    __shared__ __align__(16) bf16 Ksm[64*64];
    __shared__ __align__(16) bf16 Vtm[64*64];
    __shared__ __align__(16) bf16 Pm[4][64*64];
    const int tid = threadIdx.x;
    const int lane = tid & 63, wv = tid >> 6;
    const int kg = lane >> 4, ln = lane & 15;

    for (int e = tid; e < 512; e += 256){
        int c = e >> 3, cc = e & 7;
        const float* src = kk + ((long)(b*64 + c))*1024 + h*64 + cc*8;
        __align__(16) bf16 u[8];
        #pragma unroll
        for (int x = 0; x < 8; x++) u[x] = __float2bfloat16(src[x]);
        *reinterpret_cast<uint4*>(&Ksm[c*64 + ((cc ^ (c&7))<<3)]) = *reinterpret_cast<const uint4*>(u);
    }
    for (int e = tid; e < 4096; e += 256){
        int c = e >> 6, d0 = e & 63;
        float v = vv[((long)(b*64 + c))*1024 + h*64 + d0];
        int cc = c >> 3, ci = c & 7;
        Vtm[d0*64 + (((cc ^ (d0&7))<<3) + ci)] = __float2bfloat16(v);
    }

    bf16x8 qf[4][2];
    #pragma unroll
    for (int i = 0; i < 4; i++)
        #pragma unroll
        for (int s = 0; s < 2; s++){
            long row = (long)b*2048 + s0 + wv*64 + i*16 + ln;
            qf[i][s] = *(const bf16x8*)&q[row*1024 + h*64 + s*32 + kg*8];
        }
    __syncthreads();

    f32x4 sacc[4][4] = {};
    #pragma unroll
    for (int s = 0; s < 2; s++){
        bf16x8 kf[4];
        #pragma unroll
        for (int j = 0; j < 4; j++){
            int rb = j*16 + ln;
            kf[j] = *(const bf16x8*)&Ksm[rb*64 + (((s*4+kg) ^ (rb&7))<<3)];
        }
        #pragma unroll
        for (int i = 0; i < 4; i++)
            #pragma unroll
            for (int j = 0; j < 4; j++)
                sacc[i][j] = __builtin_amdgcn_mfma_f32_16x16x32_bf16(qf[i][s], kf[j], sacc[i][j], 0, 0, 0);
    }

    float l_val[4][4];
    #pragma unroll
    for (int i = 0; i < 4; i++){
        #pragma unroll
        for (int r = 0; r < 4; r++){
            int s_idx = s0 + wv*64 + i*16 + kg*4 + r;
            int cmax = (s_idx >> 5) + 1;
            float mx = -1e30f;
            #pragma unroll
            for (int j = 0; j < 4; j++){
                int c = j*16 + ln;
                float sc = sacc[i][j][r] * 0.125f;
                sc = (c <= cmax) ? sc : -1e30f;
                sacc[i][j][r] = sc;
                mx = fmaxf(mx, sc);
            }
            #pragma unroll
            for (int off = 1; off < 16; off <<= 1) mx = fmaxf(mx, __shfl_xor(mx, off, 64));
            float sum = 0.f;
            #pragma unroll
            for (int j = 0; j < 4; j++){
                float e = __expf(sacc[i][j][r] - mx);
                sacc[i][j][r] = e;
                sum += e;
            }
            #pragma unroll
            for (int off = 1; off < 16; off <<= 1) sum += __shfl_xor(sum, off, 64);
            l_val[i][r] = sum;
        }
    }

    bf16* Pw = &Pm[wv][0];
    #pragma unroll
    for (int i = 0; i < 4; i++)
        #pragma unroll
        for (int r = 0; r < 4; r++){
            int prow = i*16 + kg*4 + r;
            #pragma unroll
            for (int j = 0; j < 4; j++){
                int pcol = j*16 + ln;
                int cc = pcol >> 3, ci = pcol & 7;
                Pw[prow*64 + (((cc ^ (prow&7))<<3) + ci)] = __float2bfloat16(sacc[i][j][r]);
            }
        }

    f32x4 oacc[4][4] = {};
    #pragma unroll
    for (int s = 0; s < 2; s++){
        bf16x8 pf[4], vf[4];
        #pragma unroll
        for (int i = 0; i < 4; i++){
            int ra = i*16 + ln;
            pf[i] = *(const bf16x8*)&Pw[ra*64 + (((s*4+kg) ^ (ra&7))<<3)];
        }
        #pragma unroll
        for (int j = 0; j < 4; j++){
            int rb = j*16 + ln;
            vf[j] = *(const bf16x8*)&Vtm[rb*64 + (((s*4+kg) ^ (rb&7))<<3)];
        }
        #pragma unroll
        for (int i = 0; i < 4; i++)
            #pragma unroll
            for (int j = 0; j < 4; j++)
                oacc[i][j] = __builtin_amdgcn_mfma_f32_16x16x32_bf16(pf[i], vf[j], oacc[i][j], 0, 0, 0);
    }

    #pragma unroll
    for (int i = 0; i < 4; i++){
        #pragma unroll
        for (int r = 0; r < 4; r++){
            float invl = 1.f / l_val[i][r];
            long row = (long)b*2048 + s0 + wv*64 + i*16 + kg*4 + r;
            #pragma unroll
            for (int j = 0; j < 4; j++){
                long col = h*64 + j*16 + ln;
                o[row*1024 + col] = __float2bfloat16(oacc[i][j][r] * invl);
            }
        }
    }
}

// ---------------------------------------------------------------------------------
extern "C" void kernel_launch(void* const* d_in, const int* in_sizes, int n_in,
                              void* d_out, int out_size, void* d_ws, size_t ws_size,
                              hipStream_t stream)
{
    const float* tok   = (const float*)d_in[0];
    const float* crepr = (const float*)d_in[1];
    const float* cw    = (const float*)d_in[2];
    const float* n1    = (const float*)d_in[3];
    const float* cqkv  = (const float*)d_in[4];
    const float* co    = (const float*)d_in[5];
    const float* n2    = (const float*)d_in[6];
    const float* cw1   = (const float*)d_in[7];
    const float* cw2   = (const float*)d_in[8];
    const float* cw3   = (const float*)d_in[9];
    const float* dinw  = (const float*)d_in[10];
    const float* dinb  = (const float*)d_in[11];
    const float* doutw = (const float*)d_in[12];
    const float* doutb = (const float*)d_in[13];
    const float* dnw   = (const float*)d_in[14];
    const float* dfnw  = (const float*)d_in[15];
    const float* dw1   = (const float*)d_in[16];
    const float* dw2   = (const float*)d_in[17];
    const float* dw3   = (const float*)d_in[18];
    float* out = (float*)d_out;

    // Workspace layout (float units). Same footprint (~180 MB).
    float* F = (float*)d_ws;
    long off = 0;
    int*   sidx  = (int*)d_ws;        off += 1024;
    float* x_c   = F + off;           off += 262144;    // 256x1024 fp32 residual
    bf16*  h_cb  = (bf16*)(F + off);  off += 262144;    // 256x1024 bf16 (h)
    float* qkv_c = F + off;           off += 786432;    // 256x3072 fp32
    bf16*  o_cb  = (bf16*)(F + off);  off += 262144;    // 256x1024 bf16
    bf16*  g_cb  = (bf16*)(F + off);  off += 698880;    // 256x2816 bf16
    bf16*  proc_bf=(bf16*)(F + off);  off += 262144;    // 256x1024 bf16
    float* kkb   = F + off;           off += 262144;
    float* vvb   = F + off;           off += 262144;
    float* q_d   = F + off;           off += 8388608;   // partial pool low half
    float* y1    = F + off;           off += 8388608;   // pool high half / y1
    bf16*  tok_bf= (bf16*)(F + off);  off += 4194304;   // 8192x1024 bf16
    bf16*  att_bf= (bf16*)(F + off);  off += 4194304;   // 8192x1024 bf16 (late)
    bf16*  wq_bf = (bf16*)(F + off);  off += 524288;    // 1024x1024 bf16
    bf16*  wo_bf = (bf16*)(F + off);  off += 524288;
    bf16*  w1_bf = (bf16*)(F + off);  off += 1441792;   // 2816x1024 bf16
    bf16*  w3_bf = (bf16*)(F + off);  off += 1441792;
    bf16*  w2_bf = (bf16*)(F + off);  off += 1441792;   // 1024x2816 bf16
    float* t1    = F + off;
    bf16*  g_d   = (bf16*)(F + off);  off += 11534336;  // 8192x2816 bf16 (t1 overlays)
    bf16*  x2_bf = tok_bf;                              // reuse after q-proj
    bf16*  q_bf  = (bf16*)q_d;                          // q-proj bf16 output

    // Partial pool (aliases q_d..y1, 16.78M floats). Max partial use 11.53M.
    float* P  = q_d;
    float* P3 = q_d + 5767168;                          // 8*256*2816
    // bf16 k/v weights at pool top (above max partial usage; overwritten later by
    // y1 only after k/v projections complete).
    bf16*  wkv_bf = (bf16*)(q_d + 15728640);            // 2048x1024 bf16 = 1.05M floats

    // Cascade bf16 weights live in regions dead until the decoder tail:
    // g_d/t1 region (11.53M floats) and att_bf region (4.19M floats).
    bf16* cqkv_bf = (bf16*)t1;                          // 2x3072x1024 = 3.146M floats
    bf16* co_bf   = (bf16*)(t1 + 3145728);              // 2x1024x1024 = 1.049M
    bf16* cw1_bf  = (bf16*)(t1 + 4194304);              // 2x2816x1024 = 2.884M
    bf16* cw3_bf  = (bf16*)(t1 + 7077888);              // 2x2816x1024 -> ends 9.96M
    bf16* cw2_bf  = (bf16*)att_bf;                      // 2x1024x2816 = 2.884M <= 4.19M

    // ---- bf16 conversions ----
    cvt_pad_k<<<8192, 256, 0, stream>>>(tok,   tok_bf, 8192, 1024, 1024);
    cvt_pad_k<<<1024, 256, 0, stream>>>(dinw,  wq_bf,  1024, 1024, 1024);
    cvt_pad_k<<<2048, 256, 0, stream>>>(dinw + 1048576, wkv_bf, 2048, 1024, 1024);
    cvt_pad_k<<<1024, 256, 0, stream>>>(doutw, wo_bf,  1024, 1024, 1024);
    cvt_pad_k<<<2816, 256, 0, stream>>>(dw1,   w1_bf,  2730, 1024, 1024);
    cvt_pad_k<<<2816, 256, 0, stream>>>(dw3,   w3_bf,  2730, 1024, 1024);
    cvt_pad_k<<<1024, 256, 0, stream>>>(dw2,   w2_bf,  1024, 2730, 2816);
    cvt_pad_k<<<6144, 256, 0, stream>>>(cqkv,  cqkv_bf, 6144, 1024, 1024);
    cvt_pad_k<<<2048, 256, 0, stream>>>(co,    co_bf,   2048, 1024, 1024);
    for (int l = 0; l < 2; l++){
        cvt_pad_k<<<2816, 256, 0, stream>>>(cw1 + (long)l*2795520, cw1_bf + (long)l*2883584, 2730, 1024, 1024);
        cvt_pad_k<<<2816, 256, 0, stream>>>(cw3 + (long)l*2795520, cw3_bf + (long)l*2883584, 2730, 1024, 1024);
        cvt_pad_k<<<1024, 256, 0, stream>>>(cw2 + (long)l*2795520, cw2_bf + (long)l*2883584, 1024, 2730, 2816);
    }

    // ---- Cascade processor (bf16 MFMA split-K) ----
    sort_chunks_k<<<4, 64, 0, stream>>>(cw, sidx);
    gather_k<<<256, 256, 0, stream>>>(crepr, sidx, x_c);
    rms_k<bf16><<<256, 256, 0, stream>>>(x_c, n1, h_cb);
    for (int l = 0; l < 2; l++){
        // qkv: 256x3072, K=1024, KS=8 (Kc=128) -> (24,2,8)=384 blocks
        mfma_sk_k<<<dim3(24,2,8), 256, 0, stream>>>(
            h_cb, cqkv_bf + (long)l*3145728, P, 3072, 1024, 128);
        reduce_plain_k<<<3072, 256, 0, stream>>>(P, 8, nullptr, nullptr, qkv_c, 786432, 3072);
        casc_attn_k<<<64, 64, 0, stream>>>(qkv_c, o_cb);
        // o-proj: K=1024, KS=16 (Kc=64) -> (8,2,16)=256 blocks
        mfma_sk_k<<<dim3(8,2,16), 256, 0, stream>>>(
            o_cb, co_bf + (long)l*1048576, P, 1024, 1024, 64);
        reduce_res_rms_k<<<256, 256, 0, stream>>>(P, 16, 262144, x_c, n2 + l*1024, x_c, h_cb);
        // gated FFN: N=2816(pad), K=1024, KS=8 -> (22,2,8)=352 blocks each
        mfma_sk_k<<<dim3(22,2,8), 256, 0, stream>>>(
            h_cb, cw1_bf + (long)l*2883584, P,  2816, 1024, 128);
        mfma_sk_k<<<dim3(22,2,8), 256, 0, stream>>>(
            h_cb, cw3_bf + (long)l*2883584, P3, 2816, 1024, 128);
        reduce_gated_bf_k<<<2816, 256, 0, stream>>>(P, P3, 8, g_cb, 720896);
        // w2: N=1024, K=2816(pad), KS=22 (Kc=128) -> (8,2,22)=352 blocks
        mfma_sk_k<<<dim3(8,2,22), 256, 0, stream>>>(
            g_cb, cw2_bf + (long)l*2883584, P, 1024, 2816, 128);
        reduce_res_rms_k<<<256, 256, 0, stream>>>(P, 22, 262144, x_c, n1 + 1024, x_c, h_cb);
    }
    scatter_bf_k<<<256, 256, 0, stream>>>(x_c, sidx, proc_bf);

    // ---- Decoder k/v projections (bf16 MFMA split-K) ----
    mfma_sk_k<<<dim3(8,2,16), 256, 0, stream>>>(proc_bf, wkv_bf, P, 1024, 1024, 64);
    reduce_plain_k<<<1024, 256, 0, stream>>>(P, 16, dinb + 1024, nullptr, kkb, 262144, 1024);
    // FIX: wv starts at bf16 element 1024*1024 = 1048576 (was 2097152 = past end).
    mfma_sk_k<<<dim3(8,2,16), 256, 0, stream>>>(proc_bf, wkv_bf + 1048576, P, 1024, 1024, 64);
    reduce_plain_k<<<1024, 256, 0, stream>>>(P, 16, dinb + 2048, nullptr, vvb, 262144, 1024);

    // ---- Decoder big GEMMs (bf16 MFMA) ----
    // q = tok @ wq^T + bq  (bf16 out)
    mfma_gemm_k<bf16><<<dim3(8,64), 256, 0, stream>>>(tok_bf, wq_bf, dinb, nullptr, q_bf, 1024, 1024);
    dec_attn_mfma_k<<<dim3(8,16,4), 256, 0, stream>>>(q_bf, kkb, vvb, att_bf);
    // t1 = attn @ doutw^T + doutb + tok
    mfma_gemm_k<float><<<dim3(8,64), 256, 0, stream>>>(att_bf, wo_bf, doutb, tok, t1, 1024, 1024);
    // y1 = rms(t1)*dnw ; x2 = rms(y1)*dfnw  (fused)
    rms2_k<<<8192, 256, 0, stream>>>(t1, dnw, dfnw, y1, x2_bf);
    // g = silu(x2@w1^T)*(x2@w3^T) -> g_d (bf16, N padded 2816)
    mfma_gated_k<<<dim3(22,64), 512, 0, stream>>>(x2_bf, w1_bf, w3_bf, g_d, 1024, 2816);
    // y = y1 + g@w2^T -> fp32 out
    mfma_gemm_k<float><<<dim3(8,64), 256, 0, stream>>>(g_d, w2_bf, nullptr, y1, out, 1024, 2816);
}